// Round 1
// baseline (420.669 us; speedup 1.0000x reference)
//
#include <hip/hip_runtime.h>
#include <hip/hip_bf16.h>
#include <math.h>

typedef __bf16 bf16;
typedef __attribute__((ext_vector_type(8))) __bf16 bf16x8;
typedef __attribute__((ext_vector_type(4))) __bf16 bf16x4;
typedef __attribute__((ext_vector_type(4))) float f32x4;

#define NHEAD 16
#define DKH 64
#define SEQ 2048
#define DMODEL 1024

// async 16B global->LDS (wave-uniform LDS base + lane*16, per-lane global src)
__device__ __forceinline__ void gl_lds16(const void* g, void* lds) {
  __builtin_amdgcn_global_load_lds(
      (const __attribute__((address_space(1))) unsigned int*)g,
      (__attribute__((address_space(3))) unsigned int*)lds, 16, 0, 0);
}

__global__ void cvt_kernel(const float* __restrict__ in, bf16* __restrict__ out, int n4) {
  int i = blockIdx.x * blockDim.x + threadIdx.x;
  if (i < n4) {
    float4 v = ((const float4*)in)[i];
    bf16x4 o = { (bf16)v.x, (bf16)v.y, (bf16)v.z, (bf16)v.w };
    ((bf16x4*)out)[i] = o;
  }
}

// C[m,n] = sum_k A[m,k]*B[n,k]; A:[M,K] bf16 row-major, B:[N,K] bf16 row-major.
// MODE 0: fp32 C. MODE 1: bf16 C. MODE 2: bf16 C written transposed per head:
//   vT[((b*16+h)*64+dk)*2048 + s], m = b*2048+s, n = h*64+dk.
template<int MODE>
__global__ __launch_bounds__(256) void gemm_nt(const bf16* __restrict__ A,
                                               const bf16* __restrict__ Bw,
                                               float* __restrict__ Cf,
                                               bf16* __restrict__ Cb,
                                               int M, int N, int K) {
  __shared__ __attribute__((aligned(16))) bf16 As[128 * 32];
  __shared__ __attribute__((aligned(16))) bf16 Bs[128 * 32];
  const int t = threadIdx.x;
  const int w = t >> 6, l = t & 63;
  const int wr = w >> 1, wc = w & 1;
  const int tm = blockIdx.y * 128, tn = blockIdx.x * 128;
  const int srow = l >> 2, scol = (l & 3) * 8;
  const int c16 = l & 15, g4 = l >> 4;

  f32x4 acc[4][4];
#pragma unroll
  for (int i = 0; i < 4; ++i)
#pragma unroll
    for (int j = 0; j < 4; ++j) acc[i][j] = f32x4{0.f, 0.f, 0.f, 0.f};

  for (int k0 = 0; k0 < K; k0 += 32) {
#pragma unroll
    for (int j = 0; j < 2; ++j) {
      const int r0 = w * 32 + j * 16;  // wave-uniform region base row
      gl_lds16(A + (size_t)(tm + r0 + srow) * K + k0 + scol, &As[r0 * 32]);
      gl_lds16(Bw + (size_t)(tn + r0 + srow) * K + k0 + scol, &Bs[r0 * 32]);
    }
    __syncthreads();
    bf16x8 af[4], bfr[4];
#pragma unroll
    for (int i = 0; i < 4; ++i)
      af[i] = *(const bf16x8*)&As[(wr * 64 + i * 16 + c16) * 32 + g4 * 8];
#pragma unroll
    for (int j = 0; j < 4; ++j)
      bfr[j] = *(const bf16x8*)&Bs[(wc * 64 + j * 16 + c16) * 32 + g4 * 8];
#pragma unroll
    for (int i = 0; i < 4; ++i)
#pragma unroll
      for (int j = 0; j < 4; ++j)
        acc[i][j] = __builtin_amdgcn_mfma_f32_16x16x32_bf16(af[i], bfr[j], acc[i][j], 0, 0, 0);
    __syncthreads();
  }

#pragma unroll
  for (int i = 0; i < 4; ++i) {
    const int row0 = tm + wr * 64 + i * 16 + g4 * 4;
#pragma unroll
    for (int j = 0; j < 4; ++j) {
      const int col = tn + wc * 64 + j * 16 + c16;
      if (MODE == 0) {
#pragma unroll
        for (int r = 0; r < 4; ++r) Cf[(size_t)(row0 + r) * N + col] = acc[i][j][r];
      } else if (MODE == 1) {
#pragma unroll
        for (int r = 0; r < 4; ++r) Cb[(size_t)(row0 + r) * N + col] = (bf16)acc[i][j][r];
      } else {
        const int bb = row0 >> 11, s = row0 & 2047;
        const int h = col >> 6, dk = col & 63;
        bf16x4 o = { (bf16)acc[i][j][0], (bf16)acc[i][j][1],
                     (bf16)acc[i][j][2], (bf16)acc[i][j][3] };
        *(bf16x4*)&Cb[((size_t)(bb * NHEAD + h) * DKH + dk) * SEQ + s] = o;
      }
    }
  }
}

// Flash attention, causal. grid (S/64, H, B), 256 threads = 4 independent waves.
// Each wave: 16 q-rows, loops k-tiles of 64. K/V straight from global (L2-resident).
__global__ __launch_bounds__(256) void attn_kernel(const bf16* __restrict__ qb,
                                                   const bf16* __restrict__ kb,
                                                   const bf16* __restrict__ vT,
                                                   bf16* __restrict__ ob) {
  __shared__ __attribute__((aligned(16))) bf16 P[4][16][64];
  const int w = threadIdx.x >> 6, l = threadIdx.x & 63;
  const int qt = blockIdx.x, h = blockIdx.y, b = blockIdx.z;
  const int q0 = qt * 64 + w * 16;
  const int c16 = l & 15, g4 = l >> 4;

  const bf16* qp = qb + (size_t)(b * SEQ + q0 + c16) * DMODEL + h * DKH + g4 * 8;
  bf16x8 qf0 = *(const bf16x8*)qp;
  bf16x8 qf1 = *(const bf16x8*)(qp + 32);

  float mr[4], lr[4];
  f32x4 acc[4];
#pragma unroll
  for (int r = 0; r < 4; ++r) { mr[r] = -INFINITY; lr[r] = 0.f; }
#pragma unroll
  for (int j = 0; j < 4; ++j) acc[j] = f32x4{0.f, 0.f, 0.f, 0.f};

  const int kmax = q0 + 15;
  const bf16* kbase = kb + (size_t)b * SEQ * DMODEL + h * DKH;
  const bf16* vbase = vT + (size_t)(b * NHEAD + h) * DKH * SEQ;

  for (int kt = 0; kt <= kmax; kt += 64) {
    f32x4 s[4];
#pragma unroll
    for (int j = 0; j < 4; ++j) {
      const bf16* kp = kbase + (size_t)(kt + j * 16 + c16) * DMODEL + g4 * 8;
      bf16x8 kf0 = *(const bf16x8*)kp;
      bf16x8 kf1 = *(const bf16x8*)(kp + 32);
      f32x4 c = f32x4{0.f, 0.f, 0.f, 0.f};
      c = __builtin_amdgcn_mfma_f32_16x16x32_bf16(qf0, kf0, c, 0, 0, 0);
      c = __builtin_amdgcn_mfma_f32_16x16x32_bf16(qf1, kf1, c, 0, 0, 0);
      s[j] = c * 0.125f;  // 1/sqrt(64)
    }
    if (kt + 63 > q0) {  // diagonal-ish tile: apply causal mask
#pragma unroll
      for (int j = 0; j < 4; ++j) {
        const int kidx = kt + j * 16 + c16;
#pragma unroll
        for (int r = 0; r < 4; ++r) {
          const int qidx = q0 + g4 * 4 + r;
          if (kidx > qidx) s[j][r] = -INFINITY;
        }
      }
    }
    float mnew[4], scale[4];
#pragma unroll
    for (int r = 0; r < 4; ++r) {
      float v = fmaxf(fmaxf(s[0][r], s[1][r]), fmaxf(s[2][r], s[3][r]));
      v = fmaxf(v, __shfl_xor(v, 1));
      v = fmaxf(v, __shfl_xor(v, 2));
      v = fmaxf(v, __shfl_xor(v, 4));
      v = fmaxf(v, __shfl_xor(v, 8));
      mnew[r] = fmaxf(mr[r], v);
      scale[r] = __expf(mr[r] - mnew[r]);  // exp(-inf)=0 on first tile
    }
#pragma unroll
    for (int r = 0; r < 4; ++r) {
      float sum = 0.f;
#pragma unroll
      for (int j = 0; j < 4; ++j) {
        float p = __expf(s[j][r] - mnew[r]);
        s[j][r] = p;
        sum += p;
      }
      sum += __shfl_xor(sum, 1);
      sum += __shfl_xor(sum, 2);
      sum += __shfl_xor(sum, 4);
      sum += __shfl_xor(sum, 8);
      lr[r] = lr[r] * scale[r] + sum;
      mr[r] = mnew[r];
    }
    // rescale O-accum, spill P to LDS (C/D layout) for re-layout to A-frags
#pragma unroll
    for (int j = 0; j < 4; ++j)
#pragma unroll
      for (int r = 0; r < 4; ++r) {
        acc[j][r] *= scale[r];
        P[w][g4 * 4 + r][j * 16 + c16] = (bf16)s[j][r];
      }
    bf16x8 pa0 = *(const bf16x8*)&P[w][c16][g4 * 8];
    bf16x8 pa1 = *(const bf16x8*)&P[w][c16][32 + g4 * 8];
#pragma unroll
    for (int j = 0; j < 4; ++j) {
      const bf16* vp = vbase + (size_t)(j * 16 + c16) * SEQ + kt + g4 * 8;
      bf16x8 vf0 = *(const bf16x8*)vp;
      bf16x8 vf1 = *(const bf16x8*)(vp + 32);
      acc[j] = __builtin_amdgcn_mfma_f32_16x16x32_bf16(pa0, vf0, acc[j], 0, 0, 0);
      acc[j] = __builtin_amdgcn_mfma_f32_16x16x32_bf16(pa1, vf1, acc[j], 0, 0, 0);
    }
  }
#pragma unroll
  for (int j = 0; j < 4; ++j)
#pragma unroll
    for (int r = 0; r < 4; ++r) {
      float o = acc[j][r] / lr[r];
      ob[(size_t)(b * SEQ + q0 + g4 * 4 + r) * DMODEL + h * DKH + j * 16 + c16] = (bf16)o;
    }
}

extern "C" void kernel_launch(void* const* d_in, const int* in_sizes, int n_in,
                              void* d_out, int out_size, void* d_ws, size_t ws_size,
                              hipStream_t stream) {
  const float* x  = (const float*)d_in[0];
  const float* Wq = (const float*)d_in[1];
  const float* Wk = (const float*)d_in[2];
  const float* Wv = (const float*)d_in[3];
  const float* Wo = (const float*)d_in[4];
  float* out = (float*)d_out;
  char* ws = (char*)d_ws;
  const size_t MB = (size_t)1 << 20;

  bf16* xb   = (bf16*)(ws + 0 * MB);   // 4M elems = 8MB
  bf16* wqb  = (bf16*)(ws + 8 * MB);   // 1M elems = 2MB
  bf16* wkb  = (bf16*)(ws + 10 * MB);
  bf16* wvb  = (bf16*)(ws + 12 * MB);
  bf16* wob  = (bf16*)(ws + 14 * MB);
  bf16* qbuf = (bf16*)(ws + 16 * MB);  // 8MB
  bf16* kbuf = (bf16*)(ws + 24 * MB);  // 8MB
  bf16* vTb  = (bf16*)(ws + 32 * MB);  // 8MB, [b][h][dk][s]
  bf16* abuf = (bf16*)(ws + 40 * MB);  // 8MB

  cvt_kernel<<<4096, 256, 0, stream>>>(x, xb, 4194304 / 4);
  cvt_kernel<<<1024, 256, 0, stream>>>(Wq, wqb, 1048576 / 4);
  cvt_kernel<<<1024, 256, 0, stream>>>(Wk, wkb, 1048576 / 4);
  cvt_kernel<<<1024, 256, 0, stream>>>(Wv, wvb, 1048576 / 4);
  cvt_kernel<<<1024, 256, 0, stream>>>(Wo, wob, 1048576 / 4);

  dim3 gg(1024 / 128, 4096 / 128);  // (N-tiles, M-tiles) = (8, 32)
  gemm_nt<1><<<gg, 256, 0, stream>>>(xb, wqb, nullptr, qbuf, 4096, 1024, 1024);
  gemm_nt<1><<<gg, 256, 0, stream>>>(xb, wkb, nullptr, kbuf, 4096, 1024, 1024);
  gemm_nt<2><<<gg, 256, 0, stream>>>(xb, wvb, nullptr, vTb, 4096, 1024, 1024);

  attn_kernel<<<dim3(SEQ / 64, NHEAD, 2), 256, 0, stream>>>(qbuf, kbuf, vTb, abuf);

  gemm_nt<0><<<gg, 256, 0, stream>>>(abuf, wob, out, nullptr, 4096, 1024, 1024);
}

// Round 3
// 270.548 us; speedup vs baseline: 1.5549x; 1.5549x over previous
//
#include <hip/hip_runtime.h>
#include <hip/hip_bf16.h>
#include <math.h>

typedef __bf16 bf16;
typedef __attribute__((ext_vector_type(8))) __bf16 bf16x8;
typedef __attribute__((ext_vector_type(4))) __bf16 bf16x4;
typedef __attribute__((ext_vector_type(4))) float f32x4;

#define NHEAD 16
#define DKH 64
#define SEQ 2048
#define DMODEL 1024

// async 16B global->LDS (wave-uniform LDS base + lane*16, per-lane global src)
__device__ __forceinline__ void gl_lds16(const void* g, void* lds) {
  __builtin_amdgcn_global_load_lds(
      (const __attribute__((address_space(1))) unsigned int*)g,
      (__attribute__((address_space(3))) unsigned int*)lds, 16, 0, 0);
}

__global__ void cvt_kernel(const float* __restrict__ in, bf16* __restrict__ out, int n4) {
  int i = blockIdx.x * blockDim.x + threadIdx.x;
  if (i < n4) {
    float4 v = ((const float4*)in)[i];
    bf16x4 o = { (bf16)v.x, (bf16)v.y, (bf16)v.z, (bf16)v.w };
    ((bf16x4*)out)[i] = o;
  }
}

// C[m,n] = sum_k A[m,k]*B[n,k]; A:[M,K], B:[N,K] bf16 row-major.
// MODE 0: fp32 C -> Cf. MODE 3: fused QKV: col<1024 -> Cq (bf16 row-major),
// col<2048 -> Ck, col>=2048 -> Cv transposed per head vT[b][h][dk][s].
template<int MODE>
__global__ __launch_bounds__(256) void gemm_nt(const bf16* __restrict__ A,
                                               const bf16* __restrict__ Bw,
                                               float* __restrict__ Cf,
                                               bf16* __restrict__ Cq,
                                               bf16* __restrict__ Ck,
                                               bf16* __restrict__ Cv,
                                               int M, int N, int K) {
  __shared__ __attribute__((aligned(16))) bf16 As[128 * 32];
  __shared__ __attribute__((aligned(16))) bf16 Bs[128 * 32];
  const int t = threadIdx.x;
  const int w = t >> 6, l = t & 63;
  const int wr = w >> 1, wc = w & 1;
  const int tm = blockIdx.y * 128, tn = blockIdx.x * 128;
  const int srow = l >> 2, scol = (l & 3) * 8;
  const int c16 = l & 15, g4 = l >> 4;

  f32x4 acc[4][4];
#pragma unroll
  for (int i = 0; i < 4; ++i)
#pragma unroll
    for (int j = 0; j < 4; ++j) acc[i][j] = f32x4{0.f, 0.f, 0.f, 0.f};

  for (int k0 = 0; k0 < K; k0 += 32) {
#pragma unroll
    for (int j = 0; j < 2; ++j) {
      const int r0 = w * 32 + j * 16;
      gl_lds16(A + (size_t)(tm + r0 + srow) * K + k0 + scol, &As[r0 * 32]);
      gl_lds16(Bw + (size_t)(tn + r0 + srow) * K + k0 + scol, &Bs[r0 * 32]);
    }
    __syncthreads();
    bf16x8 af[4], bfr[4];
#pragma unroll
    for (int i = 0; i < 4; ++i)
      af[i] = *(const bf16x8*)&As[(wr * 64 + i * 16 + c16) * 32 + g4 * 8];
#pragma unroll
    for (int j = 0; j < 4; ++j)
      bfr[j] = *(const bf16x8*)&Bs[(wc * 64 + j * 16 + c16) * 32 + g4 * 8];
#pragma unroll
    for (int i = 0; i < 4; ++i)
#pragma unroll
      for (int j = 0; j < 4; ++j)
        acc[i][j] = __builtin_amdgcn_mfma_f32_16x16x32_bf16(af[i], bfr[j], acc[i][j], 0, 0, 0);
    __syncthreads();
  }

  const int which = tn >> 10;  // MODE 3: whole block in one of q/k/v
#pragma unroll
  for (int i = 0; i < 4; ++i) {
    const int row0 = tm + wr * 64 + i * 16 + g4 * 4;
#pragma unroll
    for (int j = 0; j < 4; ++j) {
      const int col = tn + wc * 64 + j * 16 + c16;
      if (MODE == 0) {
#pragma unroll
        for (int r = 0; r < 4; ++r) Cf[(size_t)(row0 + r) * N + col] = acc[i][j][r];
      } else {
        const int lc = col & 1023;
        if (which == 2) {  // V: transposed per head
          const int bb = row0 >> 11, s = row0 & 2047;
          const int hh = lc >> 6, dk = lc & 63;
          bf16x4 o = { (bf16)acc[i][j][0], (bf16)acc[i][j][1],
                       (bf16)acc[i][j][2], (bf16)acc[i][j][3] };
          *(bf16x4*)&Cv[((size_t)(bb * NHEAD + hh) * DKH + dk) * SEQ + s] = o;
        } else {
          bf16* dst = which ? Ck : Cq;
#pragma unroll
          for (int r = 0; r < 4; ++r)
            dst[(size_t)(row0 + r) * DMODEL + lc] = (bf16)acc[i][j][r];
        }
      }
    }
  }
}

// swizzled LDS fragment read: tile is [64 rows][64 cols] bf16, 8-elem granules,
// granule ^= (row&7) (matches the source-side pre-swizzle in staging)
__device__ __forceinline__ bf16x8 lds_frag(const bf16* T, int row, int gran) {
  return *(const bf16x8*)&T[row * 64 + ((gran ^ (row & 7)) << 3)];
}

// Flash attention, causal. grid (S/128, H, B), 256 threads = 4 waves x 32 q-rows.
// K/V tiles (64 kv) staged once per block into swizzled LDS, double-buffered.
__global__ __launch_bounds__(256) void attn_kernel(const bf16* __restrict__ qb,
                                                   const bf16* __restrict__ kb,
                                                   const bf16* __restrict__ vT,
                                                   bf16* __restrict__ ob) {
  __shared__ __attribute__((aligned(16))) bf16 Kt[2][64 * 64];
  __shared__ __attribute__((aligned(16))) bf16 Vt[2][64 * 64];
  __shared__ __attribute__((aligned(16))) bf16 Pb[4][32 * 64];
  const int w = threadIdx.x >> 6, l = threadIdx.x & 63;
  const int qt = gridDim.x - 1 - blockIdx.x;  // heavy tiles dispatch first
  const int h = blockIdx.y, b = blockIdx.z;
  const int q0w = qt * 128 + w * 32;
  const int c16 = l & 15, g4 = l >> 4;
  const int r8 = l >> 3;
  const int sg = ((l & 7) ^ (r8 & 7)) * 8;  // pre-swizzled src col (elems)

  const bf16* kbase = kb + (size_t)b * SEQ * DMODEL + h * DKH;
  const bf16* vbase = vT + (size_t)(b * NHEAD + h) * DKH * SEQ;

  // Q fragments (A-operand): row = q0w + i*16 + c16, k = d*32 + g4*8
  bf16x8 qf[2][2];
#pragma unroll
  for (int i = 0; i < 2; ++i)
#pragma unroll
    for (int d = 0; d < 2; ++d)
      qf[i][d] = *(const bf16x8*)(qb + (size_t)(b * SEQ + q0w + i * 16 + c16) * DMODEL +
                                  h * DKH + d * 32 + g4 * 8);

  float m[2][4], lsum[2][4];
  f32x4 acc[2][4];
#pragma unroll
  for (int i = 0; i < 2; ++i)
#pragma unroll
    for (int r = 0; r < 4; ++r) { m[i][r] = -INFINITY; lsum[i][r] = 0.f; }
#pragma unroll
  for (int i = 0; i < 2; ++i)
#pragma unroll
    for (int n = 0; n < 4; ++n) acc[i][n] = f32x4{0.f, 0.f, 0.f, 0.f};

  const int T = qt * 2 + 2;              // kv tiles this block processes
  const int tmax_w = (q0w + 31) >> 6;    // last tile this wave needs

  // stage tile t into buf: K rows [kv][64d], V rows [dk][64kv], src pre-swizzled
  auto stage = [&](int buf, int t) {
    const int kt0 = t * 64;
#pragma unroll
    for (int c = 0; c < 2; ++c) {
      const int row = w * 16 + c * 8;  // wave-uniform segment base
      gl_lds16(kbase + (size_t)(kt0 + row + r8) * DMODEL + sg, &Kt[buf][row * 64]);
      gl_lds16(vbase + (size_t)(row + r8) * SEQ + kt0 + sg, &Vt[buf][row * 64]);
    }
  };

  stage(0, 0);
  __syncthreads();

  for (int t = 0; t < T; ++t) {
    const int cur = t & 1;
    if (t + 1 < T) stage(cur ^ 1, t + 1);
    if (t <= tmax_w) {
      const int kt0 = t * 64;
      // ---- QK^T: s[i][j] row q = q0w+i*16+g4*4+r, col kv = kt0+j*16+c16
      f32x4 s[2][4];
#pragma unroll
      for (int j = 0; j < 4; ++j) {
        bf16x8 kf0 = lds_frag(Kt[cur], j * 16 + c16, g4);
        bf16x8 kf1 = lds_frag(Kt[cur], j * 16 + c16, 4 + g4);
#pragma unroll
        for (int i = 0; i < 2; ++i) {
          f32x4 c = f32x4{0.f, 0.f, 0.f, 0.f};
          c = __builtin_amdgcn_mfma_f32_16x16x32_bf16(qf[i][0], kf0, c, 0, 0, 0);
          c = __builtin_amdgcn_mfma_f32_16x16x32_bf16(qf[i][1], kf1, c, 0, 0, 0);
          s[i][j] = c * 0.125f;  // 1/sqrt(64)
        }
      }
      if (kt0 + 63 > q0w) {  // causal mask on diagonal-ish tiles
#pragma unroll
        for (int j = 0; j < 4; ++j) {
          const int kidx = kt0 + j * 16 + c16;
#pragma unroll
          for (int i = 0; i < 2; ++i)
#pragma unroll
            for (int r = 0; r < 4; ++r)
              if (kidx > q0w + i * 16 + g4 * 4 + r) s[i][j][r] = -INFINITY;
        }
      }
      // ---- online softmax (reduce over j in-lane, then 16-lane shfl)
      float scale[2][4];
#pragma unroll
      for (int i = 0; i < 2; ++i)
#pragma unroll
        for (int r = 0; r < 4; ++r) {
          float v = fmaxf(fmaxf(s[i][0][r], s[i][1][r]), fmaxf(s[i][2][r], s[i][3][r]));
          v = fmaxf(v, __shfl_xor(v, 1));
          v = fmaxf(v, __shfl_xor(v, 2));
          v = fmaxf(v, __shfl_xor(v, 4));
          v = fmaxf(v, __shfl_xor(v, 8));
          const float mn = fmaxf(m[i][r], v);
          scale[i][r] = __expf(m[i][r] - mn);
          float sum = 0.f;
#pragma unroll
          for (int j = 0; j < 4; ++j) {
            float p = __expf(s[i][j][r] - mn);
            s[i][j][r] = p;
            sum += p;
          }
          sum += __shfl_xor(sum, 1);
          sum += __shfl_xor(sum, 2);
          sum += __shfl_xor(sum, 4);
          sum += __shfl_xor(sum, 8);
          lsum[i][r] = lsum[i][r] * scale[i][r] + sum;
          m[i][r] = mn;
        }
      // ---- rescale O, spill P (bf16) to swizzled LDS
      bf16* P = &Pb[w][0];
#pragma unroll
      for (int i = 0; i < 2; ++i)
#pragma unroll
        for (int j = 0; j < 4; ++j)
#pragma unroll
          for (int r = 0; r < 4; ++r) {
            if (j == 0) {
              acc[i][0][r] *= scale[i][r]; acc[i][1][r] *= scale[i][r];
              acc[i][2][r] *= scale[i][r]; acc[i][3][r] *= scale[i][r];
            }
            const int row = i * 16 + g4 * 4 + r, col = j * 16 + c16;
            P[row * 64 + (((col >> 3) ^ (row & 7)) << 3) + (col & 7)] = (bf16)s[i][j][r];
          }
      // ---- PV: A = P rows q (c16), k = kv; B = V rows dk (c16), k = kv
      bf16x8 pa[2][2];
#pragma unroll
      for (int ip = 0; ip < 2; ++ip)
#pragma unroll
        for (int d = 0; d < 2; ++d)
          pa[ip][d] = lds_frag(P, ip * 16 + c16, d * 4 + g4);
#pragma unroll
      for (int n = 0; n < 4; ++n) {
        bf16x8 vf0 = lds_frag(Vt[cur], n * 16 + c16, g4);
        bf16x8 vf1 = lds_frag(Vt[cur], n * 16 + c16, 4 + g4);
#pragma unroll
        for (int ip = 0; ip < 2; ++ip) {
          acc[ip][n] = __builtin_amdgcn_mfma_f32_16x16x32_bf16(pa[ip][0], vf0, acc[ip][n], 0, 0, 0);
          acc[ip][n] = __builtin_amdgcn_mfma_f32_16x16x32_bf16(pa[ip][1], vf1, acc[ip][n], 0, 0, 0);
        }
      }
    }
    __syncthreads();
  }

#pragma unroll
  for (int ip = 0; ip < 2; ++ip)
#pragma unroll
    for (int n = 0; n < 4; ++n)
#pragma unroll
      for (int r = 0; r < 4; ++r) {
        float o = acc[ip][n][r] / lsum[ip][r];
        ob[(size_t)(b * SEQ + q0w + ip * 16 + g4 * 4 + r) * DMODEL +
           h * DKH + n * 16 + c16] = (bf16)o;
      }
}

extern "C" void kernel_launch(void* const* d_in, const int* in_sizes, int n_in,
                              void* d_out, int out_size, void* d_ws, size_t ws_size,
                              hipStream_t stream) {
  const float* x  = (const float*)d_in[0];
  const float* Wq = (const float*)d_in[1];
  const float* Wk = (const float*)d_in[2];
  const float* Wv = (const float*)d_in[3];
  const float* Wo = (const float*)d_in[4];
  float* out = (float*)d_out;
  char* ws = (char*)d_ws;
  const size_t MB = (size_t)1 << 20;

  // wqb/wkb/wvb contiguous -> one [3072][1024] weight matrix for fused QKV
  bf16* xb   = (bf16*)(ws + 0 * MB);   // 8MB
  bf16* wqb  = (bf16*)(ws + 8 * MB);   // 2MB
  bf16* wkb  = (bf16*)(ws + 10 * MB);  // 2MB
  bf16* wvb  = (bf16*)(ws + 12 * MB);  // 2MB
  bf16* wob  = (bf16*)(ws + 14 * MB);  // 2MB
  bf16* qbuf = (bf16*)(ws + 16 * MB);  // 8MB
  bf16* kbuf = (bf16*)(ws + 24 * MB);  // 8MB
  bf16* vTb  = (bf16*)(ws + 32 * MB);  // 8MB, [b][h][dk][s]
  bf16* abuf = (bf16*)(ws + 40 * MB);  // 8MB

  cvt_kernel<<<4096, 256, 0, stream>>>(x, xb, 4194304 / 4);
  cvt_kernel<<<1024, 256, 0, stream>>>(Wq, wqb, 1048576 / 4);
  cvt_kernel<<<1024, 256, 0, stream>>>(Wk, wkb, 1048576 / 4);
  cvt_kernel<<<1024, 256, 0, stream>>>(Wv, wvb, 1048576 / 4);
  cvt_kernel<<<1024, 256, 0, stream>>>(Wo, wob, 1048576 / 4);

  // fused QKV projection: N = 3072, 768 blocks (~3/CU)
  gemm_nt<3><<<dim3(3072 / 128, 4096 / 128), 256, 0, stream>>>(
      xb, wqb, nullptr, qbuf, kbuf, vTb, 4096, 3072, 1024);

  attn_kernel<<<dim3(SEQ / 128, NHEAD, 2), 256, 0, stream>>>(qbuf, kbuf, vTb, abuf);

  gemm_nt<0><<<dim3(1024 / 128, 4096 / 128), 256, 0, stream>>>(
      abuf, wob, out, nullptr, nullptr, nullptr, 4096, 1024, 1024);
}

// Round 4
// 227.902 us; speedup vs baseline: 1.8458x; 1.1871x over previous
//
#include <hip/hip_runtime.h>
#include <hip/hip_bf16.h>
#include <math.h>

typedef __bf16 bf16;
typedef __attribute__((ext_vector_type(8))) __bf16 bf16x8;
typedef __attribute__((ext_vector_type(4))) __bf16 bf16x4;
typedef __attribute__((ext_vector_type(4))) float f32x4;

#define NHEAD 16
#define DKH 64
#define SEQ 2048
#define DMODEL 1024

// async 16B global->LDS (wave-uniform LDS base + lane*16, per-lane global src)
__device__ __forceinline__ void gl_lds16(const void* g, void* lds) {
  __builtin_amdgcn_global_load_lds(
      (const __attribute__((address_space(1))) unsigned int*)g,
      (__attribute__((address_space(3))) unsigned int*)lds, 16, 0, 0);
}

// one launch converting x + 4 weight matrices fp32->bf16 (4-elem units)
__global__ void cvt5_kernel(const float* __restrict__ x, const float* __restrict__ wq,
                            const float* __restrict__ wk, const float* __restrict__ wv,
                            const float* __restrict__ wo, bf16* __restrict__ xb,
                            bf16* __restrict__ wqb, bf16* __restrict__ wkb,
                            bf16* __restrict__ wvb, bf16* __restrict__ wob) {
  int i = blockIdx.x * blockDim.x + threadIdx.x;  // [0, 2097152)
  const float* src; bf16* dst; int li;
  if (i < 1048576)      { src = x;  dst = xb;  li = i; }
  else if (i < 1310720) { src = wq; dst = wqb; li = i - 1048576; }
  else if (i < 1572864) { src = wk; dst = wkb; li = i - 1310720; }
  else if (i < 1835008) { src = wv; dst = wvb; li = i - 1572864; }
  else                  { src = wo; dst = wob; li = i - 1835008; }
  float4 v = ((const float4*)src)[li];
  bf16x4 o = { (bf16)v.x, (bf16)v.y, (bf16)v.z, (bf16)v.w };
  ((bf16x4*)dst)[li] = o;
}

// C[m,n] = sum_k A[m,k]*B[n,k]; A:[M,K], B:[N,K] bf16 row-major.
// MODE 0: fp32 C -> Cf. MODE 3: fused QKV: col<1024 -> Cq (bf16 row-major),
// col<2048 -> Ck, col>=2048 -> Cv transposed per head vT[b][h][dk][s].
template<int MODE>
__global__ __launch_bounds__(256) void gemm_nt(const bf16* __restrict__ A,
                                               const bf16* __restrict__ Bw,
                                               float* __restrict__ Cf,
                                               bf16* __restrict__ Cq,
                                               bf16* __restrict__ Ck,
                                               bf16* __restrict__ Cv,
                                               int M, int N, int K) {
  __shared__ __attribute__((aligned(16))) bf16 As[128 * 32];
  __shared__ __attribute__((aligned(16))) bf16 Bs[128 * 32];
  const int t = threadIdx.x;
  const int w = t >> 6, l = t & 63;
  const int wr = w >> 1, wc = w & 1;
  // XCD-chunked swizzle (nwg divisible by 8): contiguous tile chunk per XCD
  const int lin = blockIdx.y * gridDim.x + blockIdx.x;
  const int cpx = (gridDim.x * gridDim.y) >> 3;
  const int swz = (lin & 7) * cpx + (lin >> 3);
  const int tm = (swz / gridDim.x) * 128, tn = (swz % gridDim.x) * 128;
  const int srow = l >> 2, scol = (l & 3) * 8;
  const int c16 = l & 15, g4 = l >> 4;

  f32x4 acc[4][4];
#pragma unroll
  for (int i = 0; i < 4; ++i)
#pragma unroll
    for (int j = 0; j < 4; ++j) acc[i][j] = f32x4{0.f, 0.f, 0.f, 0.f};

  for (int k0 = 0; k0 < K; k0 += 32) {
#pragma unroll
    for (int j = 0; j < 2; ++j) {
      const int r0 = w * 32 + j * 16;
      gl_lds16(A + (size_t)(tm + r0 + srow) * K + k0 + scol, &As[r0 * 32]);
      gl_lds16(Bw + (size_t)(tn + r0 + srow) * K + k0 + scol, &Bs[r0 * 32]);
    }
    __syncthreads();
    bf16x8 af[4], bfr[4];
#pragma unroll
    for (int i = 0; i < 4; ++i)
      af[i] = *(const bf16x8*)&As[(wr * 64 + i * 16 + c16) * 32 + g4 * 8];
#pragma unroll
    for (int j = 0; j < 4; ++j)
      bfr[j] = *(const bf16x8*)&Bs[(wc * 64 + j * 16 + c16) * 32 + g4 * 8];
#pragma unroll
    for (int i = 0; i < 4; ++i)
#pragma unroll
      for (int j = 0; j < 4; ++j)
        acc[i][j] = __builtin_amdgcn_mfma_f32_16x16x32_bf16(af[i], bfr[j], acc[i][j], 0, 0, 0);
    __syncthreads();
  }

  const int which = tn >> 10;  // MODE 3: whole block in one of q/k/v
#pragma unroll
  for (int i = 0; i < 4; ++i) {
    const int row0 = tm + wr * 64 + i * 16 + g4 * 4;
#pragma unroll
    for (int j = 0; j < 4; ++j) {
      const int col = tn + wc * 64 + j * 16 + c16;
      if (MODE == 0) {
#pragma unroll
        for (int r = 0; r < 4; ++r) Cf[(size_t)(row0 + r) * N + col] = acc[i][j][r];
      } else {
        const int lc = col & 1023;
        if (which == 2) {  // V: transposed per head
          const int bb = row0 >> 11, s = row0 & 2047;
          const int hh = lc >> 6, dk = lc & 63;
          bf16x4 o = { (bf16)acc[i][j][0], (bf16)acc[i][j][1],
                       (bf16)acc[i][j][2], (bf16)acc[i][j][3] };
          *(bf16x4*)&Cv[((size_t)(bb * NHEAD + hh) * DKH + dk) * SEQ + s] = o;
        } else {
          bf16* dst = which ? Ck : Cq;
#pragma unroll
          for (int r = 0; r < 4; ++r)
            dst[(size_t)(row0 + r) * DMODEL + lc] = (bf16)acc[i][j][r];
        }
      }
    }
  }
}

// swizzled LDS fragment read: tile is [rows][64 cols] bf16, 8-elem granules,
// granule ^= (row&7) (matches the source-side pre-swizzle in staging)
__device__ __forceinline__ bf16x8 lds_frag(const bf16* T, int row, int gran) {
  return *(const bf16x8*)&T[row * 64 + ((gran ^ (row & 7)) << 3)];
}

__device__ __forceinline__ f32x4 vmax4(f32x4 a, f32x4 b) {
  return f32x4{ fmaxf(a[0], b[0]), fmaxf(a[1], b[1]),
                fmaxf(a[2], b[2]), fmaxf(a[3], b[3]) };
}

// Flash attention, causal. grid (S/128, H, B), 256 threads = 4 waves x 32 q-rows.
// K/V staged in swizzled LDS (dbuf). QK^T computed SWAPPED (rows=kv, cols=q) so
// each lane holds 16 scores of ONE q-row -> softmax reduce is in-lane + 2 shfl.
__global__ __launch_bounds__(256) void attn_kernel(const bf16* __restrict__ qb,
                                                   const bf16* __restrict__ kb,
                                                   const bf16* __restrict__ vT,
                                                   bf16* __restrict__ ob) {
  __shared__ __attribute__((aligned(16))) bf16 Kt[2][64 * 64];
  __shared__ __attribute__((aligned(16))) bf16 Vt[2][64 * 64];
  __shared__ __attribute__((aligned(16))) bf16 Pb[4][32 * 64];
  const int w = threadIdx.x >> 6, l = threadIdx.x & 63;
  const int qt = gridDim.x - 1 - blockIdx.x;  // heavy tiles dispatch first
  const int h = blockIdx.y, b = blockIdx.z;
  const int q0w = qt * 128 + w * 32;
  const int c16 = l & 15, g4 = l >> 4;
  const int r8 = l >> 3;
  const int sg = ((l & 7) ^ (r8 & 7)) * 8;  // pre-swizzled src col (elems)

  const float SC = 0.125f * 1.44269504089f;  // 1/sqrt(dk) * log2(e): exp -> exp2

  const bf16* kbase = kb + (size_t)b * SEQ * DMODEL + h * DKH;
  const bf16* vbase = vT + (size_t)(b * NHEAD + h) * DKH * SEQ;

  // Q fragments (now the B-operand; same lane layout): row q0w+i*16+c16
  bf16x8 qf[2][2];
#pragma unroll
  for (int i = 0; i < 2; ++i)
#pragma unroll
    for (int d = 0; d < 2; ++d)
      qf[i][d] = *(const bf16x8*)(qb + (size_t)(b * SEQ + q0w + i * 16 + c16) * DMODEL +
                                  h * DKH + d * 32 + g4 * 8);

  float m[2] = { -INFINITY, -INFINITY }, lsum[2] = { 0.f, 0.f };
  f32x4 acc[2][4];
#pragma unroll
  for (int i = 0; i < 2; ++i)
#pragma unroll
    for (int n = 0; n < 4; ++n) acc[i][n] = f32x4{0.f, 0.f, 0.f, 0.f};

  const int T = qt * 2 + 2;              // kv tiles this block processes
  const int tmax_w = (q0w + 31) >> 6;    // last tile this wave needs

  auto stage = [&](int buf, int t) {
    const int kt0 = t * 64;
#pragma unroll
    for (int c = 0; c < 2; ++c) {
      const int row = w * 16 + c * 8;  // wave-uniform segment base
      gl_lds16(kbase + (size_t)(kt0 + row + r8) * DMODEL + sg, &Kt[buf][row * 64]);
      gl_lds16(vbase + (size_t)(row + r8) * SEQ + kt0 + sg, &Vt[buf][row * 64]);
    }
  };

  stage(0, 0);
  __syncthreads();

  for (int t = 0; t < T; ++t) {
    const int cur = t & 1;
    if (t + 1 < T) stage(cur ^ 1, t + 1);
    if (t <= tmax_w) {
      const int kt0 = t * 64;
      // ---- QK^T swapped: s[i][j] row kv = kt0+j*16+g4*4+r, col q = q0w+i*16+c16
      f32x4 s[2][4];
#pragma unroll
      for (int j = 0; j < 4; ++j) {
        bf16x8 kf0 = lds_frag(Kt[cur], j * 16 + c16, g4);
        bf16x8 kf1 = lds_frag(Kt[cur], j * 16 + c16, 4 + g4);
#pragma unroll
        for (int i = 0; i < 2; ++i) {
          f32x4 c = f32x4{0.f, 0.f, 0.f, 0.f};
          c = __builtin_amdgcn_mfma_f32_16x16x32_bf16(kf0, qf[i][0], c, 0, 0, 0);
          c = __builtin_amdgcn_mfma_f32_16x16x32_bf16(kf1, qf[i][1], c, 0, 0, 0);
          s[i][j] = c * SC;
        }
      }
      if (kt0 + 63 > q0w) {  // causal mask on diagonal-ish tiles
#pragma unroll
        for (int i = 0; i < 2; ++i) {
          const int qidx = q0w + i * 16 + c16;
#pragma unroll
          for (int j = 0; j < 4; ++j)
#pragma unroll
            for (int r = 0; r < 4; ++r)
              if (kt0 + j * 16 + g4 * 4 + r > qidx) s[i][j][r] = -INFINITY;
        }
      }
      // ---- online softmax: all 16 scores of q-row (i,c16) are in-lane
      float scale_v[2];
#pragma unroll
      for (int i = 0; i < 2; ++i) {
        f32x4 t01 = vmax4(s[i][0], s[i][1]);
        f32x4 t23 = vmax4(s[i][2], s[i][3]);
        f32x4 tt = vmax4(t01, t23);
        float v = fmaxf(fmaxf(tt[0], tt[1]), fmaxf(tt[2], tt[3]));
        v = fmaxf(v, __shfl_xor(v, 16));
        v = fmaxf(v, __shfl_xor(v, 32));
        const float mn = fmaxf(m[i], v);
        scale_v[i] = __builtin_amdgcn_exp2f(m[i] - mn);
        f32x4 ps = f32x4{0.f, 0.f, 0.f, 0.f};
#pragma unroll
        for (int j = 0; j < 4; ++j)
#pragma unroll
          for (int r = 0; r < 4; ++r) {
            float p = __builtin_amdgcn_exp2f(s[i][j][r] - mn);
            s[i][j][r] = p;
            ps[r] += p;
          }
        float rs = (ps[0] + ps[1]) + (ps[2] + ps[3]);
        rs += __shfl_xor(rs, 16);
        rs += __shfl_xor(rs, 32);
        lsum[i] = lsum[i] * scale_v[i] + rs;
        m[i] = mn;
      }
      // ---- spill P: lane's 4 consecutive kv (r=0..3) -> one b64 store
      bf16* P = &Pb[w][0];
#pragma unroll
      for (int i = 0; i < 2; ++i) {
        const int row = i * 16 + c16;
#pragma unroll
        for (int j = 0; j < 4; ++j) {
          const int col = j * 16 + g4 * 4;
          bf16x4 pk = { (bf16)s[i][j][0], (bf16)s[i][j][1],
                        (bf16)s[i][j][2], (bf16)s[i][j][3] };
          *(bf16x4*)&P[row * 64 + (((col >> 3) ^ (row & 7)) << 3) + (col & 7)] = pk;
        }
      }
      // ---- redistribute rescale factor to acc layout (q = ip*16+g4*4+r)
      float sc[2][4];
#pragma unroll
      for (int ip = 0; ip < 2; ++ip)
#pragma unroll
        for (int r = 0; r < 4; ++r) sc[ip][r] = __shfl(scale_v[ip], g4 * 4 + r);
#pragma unroll
      for (int ip = 0; ip < 2; ++ip)
#pragma unroll
        for (int n = 0; n < 4; ++n)
#pragma unroll
          for (int r = 0; r < 4; ++r) acc[ip][n][r] *= sc[ip][r];
      // ---- PV: A = P rows q, B = V rows dk
      bf16x8 pa[2][2];
#pragma unroll
      for (int ip = 0; ip < 2; ++ip)
#pragma unroll
        for (int d = 0; d < 2; ++d)
          pa[ip][d] = lds_frag(P, ip * 16 + c16, d * 4 + g4);
#pragma unroll
      for (int n = 0; n < 4; ++n) {
        bf16x8 vf0 = lds_frag(Vt[cur], n * 16 + c16, g4);
        bf16x8 vf1 = lds_frag(Vt[cur], n * 16 + c16, 4 + g4);
#pragma unroll
        for (int ip = 0; ip < 2; ++ip) {
          acc[ip][n] = __builtin_amdgcn_mfma_f32_16x16x32_bf16(pa[ip][0], vf0, acc[ip][n], 0, 0, 0);
          acc[ip][n] = __builtin_amdgcn_mfma_f32_16x16x32_bf16(pa[ip][1], vf1, acc[ip][n], 0, 0, 0);
        }
      }
    }
    __syncthreads();
  }

  // epilogue: redistribute lsum to acc layout, normalize, store
  float ls[2][4];
#pragma unroll
  for (int ip = 0; ip < 2; ++ip)
#pragma unroll
    for (int r = 0; r < 4; ++r) ls[ip][r] = __shfl(lsum[ip], g4 * 4 + r);
#pragma unroll
  for (int ip = 0; ip < 2; ++ip)
#pragma unroll
    for (int n = 0; n < 4; ++n)
#pragma unroll
      for (int r = 0; r < 4; ++r) {
        float o = acc[ip][n][r] / ls[ip][r];
        ob[(size_t)(b * SEQ + q0w + ip * 16 + g4 * 4 + r) * DMODEL +
           h * DKH + n * 16 + c16] = (bf16)o;
      }
}

extern "C" void kernel_launch(void* const* d_in, const int* in_sizes, int n_in,
                              void* d_out, int out_size, void* d_ws, size_t ws_size,
                              hipStream_t stream) {
  const float* x  = (const float*)d_in[0];
  const float* Wq = (const float*)d_in[1];
  const float* Wk = (const float*)d_in[2];
  const float* Wv = (const float*)d_in[3];
  const float* Wo = (const float*)d_in[4];
  float* out = (float*)d_out;
  char* ws = (char*)d_ws;
  const size_t MB = (size_t)1 << 20;

  // wqb/wkb/wvb contiguous -> one [3072][1024] weight matrix for fused QKV
  bf16* xb   = (bf16*)(ws + 0 * MB);   // 8MB
  bf16* wqb  = (bf16*)(ws + 8 * MB);   // 2MB
  bf16* wkb  = (bf16*)(ws + 10 * MB);  // 2MB
  bf16* wvb  = (bf16*)(ws + 12 * MB);  // 2MB
  bf16* wob  = (bf16*)(ws + 14 * MB);  // 2MB
  bf16* qbuf = (bf16*)(ws + 16 * MB);  // 8MB
  bf16* kbuf = (bf16*)(ws + 24 * MB);  // 8MB
  bf16* vTb  = (bf16*)(ws + 32 * MB);  // 8MB, [b][h][dk][s]
  bf16* abuf = (bf16*)(ws + 40 * MB);  // 8MB

  cvt5_kernel<<<8192, 256, 0, stream>>>(x, Wq, Wk, Wv, Wo, xb, wqb, wkb, wvb, wob);

  // fused QKV projection: N = 3072, 768 blocks (~3/CU)
  gemm_nt<3><<<dim3(3072 / 128, 4096 / 128), 256, 0, stream>>>(
      xb, wqb, nullptr, qbuf, kbuf, vTb, 4096, 3072, 1024);

  attn_kernel<<<dim3(SEQ / 128, NHEAD, 2), 256, 0, stream>>>(qbuf, kbuf, vTb, abuf);

  gemm_nt<0><<<dim3(1024 / 128, 4096 / 128), 256, 0, stream>>>(
      abuf, wob, out, nullptr, nullptr, nullptr, 4096, 1024, 1024);
}

// Round 5
// 194.852 us; speedup vs baseline: 2.1589x; 1.1696x over previous
//
#include <hip/hip_runtime.h>
#include <hip/hip_bf16.h>
#include <math.h>

typedef __bf16 bf16;
typedef __attribute__((ext_vector_type(8))) __bf16 bf16x8;
typedef __attribute__((ext_vector_type(4))) __bf16 bf16x4;
typedef __attribute__((ext_vector_type(4))) float f32x4;

#define NHEAD 16
#define DKH 64
#define SEQ 2048
#define DMODEL 1024

// async 16B global->LDS (wave-uniform LDS base + lane*16, per-lane global src)
__device__ __forceinline__ void gl_lds16(const void* g, void* lds) {
  __builtin_amdgcn_global_load_lds(
      (const __attribute__((address_space(1))) unsigned int*)g,
      (__attribute__((address_space(3))) unsigned int*)lds, 16, 0, 0);
}

// one launch converting x + 4 weight matrices fp32->bf16 (4-elem units)
__global__ void cvt5_kernel(const float* __restrict__ x, const float* __restrict__ wq,
                            const float* __restrict__ wk, const float* __restrict__ wv,
                            const float* __restrict__ wo, bf16* __restrict__ xb,
                            bf16* __restrict__ wqb, bf16* __restrict__ wkb,
                            bf16* __restrict__ wvb, bf16* __restrict__ wob) {
  int i = blockIdx.x * blockDim.x + threadIdx.x;  // [0, 2097152)
  const float* src; bf16* dst; int li;
  if (i < 1048576)      { src = x;  dst = xb;  li = i; }
  else if (i < 1310720) { src = wq; dst = wqb; li = i - 1048576; }
  else if (i < 1572864) { src = wk; dst = wkb; li = i - 1310720; }
  else if (i < 1835008) { src = wv; dst = wvb; li = i - 1572864; }
  else                  { src = wo; dst = wob; li = i - 1835008; }
  float4 v = ((const float4*)src)[li];
  bf16x4 o = { (bf16)v.x, (bf16)v.y, (bf16)v.z, (bf16)v.w };
  ((bf16x4*)dst)[li] = o;
}

// C[m,n] = sum_k A[m,k]*B[n,k]; A:[M,K], B:[N,K] bf16 row-major.
// MODE 0: fp32 C -> Cf. MODE 3: fused QKV: col<1024 -> Cq (bf16 row-major),
// col<2048 -> Ck, col>=2048 -> Cv transposed per head vT[b][h][dk][s].
template<int MODE>
__global__ __launch_bounds__(256) void gemm_nt(const bf16* __restrict__ A,
                                               const bf16* __restrict__ Bw,
                                               float* __restrict__ Cf,
                                               bf16* __restrict__ Cq,
                                               bf16* __restrict__ Ck,
                                               bf16* __restrict__ Cv,
                                               int M, int N, int K) {
  __shared__ __attribute__((aligned(16))) bf16 As[128 * 32];
  __shared__ __attribute__((aligned(16))) bf16 Bs[128 * 32];
  const int t = threadIdx.x;
  const int w = t >> 6, l = t & 63;
  const int wr = w >> 1, wc = w & 1;
  // XCD-chunked swizzle (nwg divisible by 8): contiguous tile chunk per XCD
  const int lin = blockIdx.y * gridDim.x + blockIdx.x;
  const int cpx = (gridDim.x * gridDim.y) >> 3;
  const int swz = (lin & 7) * cpx + (lin >> 3);
  const int tm = (swz / gridDim.x) * 128, tn = (swz % gridDim.x) * 128;
  const int srow = l >> 2, scol = (l & 3) * 8;
  const int c16 = l & 15, g4 = l >> 4;

  f32x4 acc[4][4];
#pragma unroll
  for (int i = 0; i < 4; ++i)
#pragma unroll
    for (int j = 0; j < 4; ++j) acc[i][j] = f32x4{0.f, 0.f, 0.f, 0.f};

  for (int k0 = 0; k0 < K; k0 += 32) {
#pragma unroll
    for (int j = 0; j < 2; ++j) {
      const int r0 = w * 32 + j * 16;
      gl_lds16(A + (size_t)(tm + r0 + srow) * K + k0 + scol, &As[r0 * 32]);
      gl_lds16(Bw + (size_t)(tn + r0 + srow) * K + k0 + scol, &Bs[r0 * 32]);
    }
    __syncthreads();
    bf16x8 af[4], bfr[4];
#pragma unroll
    for (int i = 0; i < 4; ++i)
      af[i] = *(const bf16x8*)&As[(wr * 64 + i * 16 + c16) * 32 + g4 * 8];
#pragma unroll
    for (int j = 0; j < 4; ++j)
      bfr[j] = *(const bf16x8*)&Bs[(wc * 64 + j * 16 + c16) * 32 + g4 * 8];
#pragma unroll
    for (int i = 0; i < 4; ++i)
#pragma unroll
      for (int j = 0; j < 4; ++j)
        acc[i][j] = __builtin_amdgcn_mfma_f32_16x16x32_bf16(af[i], bfr[j], acc[i][j], 0, 0, 0);
    __syncthreads();
  }

  const int which = tn >> 10;  // MODE 3: whole block in one of q/k/v
#pragma unroll
  for (int i = 0; i < 4; ++i) {
    const int row0 = tm + wr * 64 + i * 16 + g4 * 4;
#pragma unroll
    for (int j = 0; j < 4; ++j) {
      const int col = tn + wc * 64 + j * 16 + c16;
      if (MODE == 0) {
#pragma unroll
        for (int r = 0; r < 4; ++r) Cf[(size_t)(row0 + r) * N + col] = acc[i][j][r];
      } else {
        const int lc = col & 1023;
        if (which == 2) {  // V: transposed per head
          const int bb = row0 >> 11, s = row0 & 2047;
          const int hh = lc >> 6, dk = lc & 63;
          bf16x4 o = { (bf16)acc[i][j][0], (bf16)acc[i][j][1],
                       (bf16)acc[i][j][2], (bf16)acc[i][j][3] };
          *(bf16x4*)&Cv[((size_t)(bb * NHEAD + hh) * DKH + dk) * SEQ + s] = o;
        } else {
          bf16* dst = which ? Ck : Cq;
#pragma unroll
          for (int r = 0; r < 4; ++r)
            dst[(size_t)(row0 + r) * DMODEL + lc] = (bf16)acc[i][j][r];
        }
      }
    }
  }
}

// swizzled LDS fragment read: tile is [rows][64 cols] bf16, 8-elem granules,
// granule ^= (row&7) (matches the source-side pre-swizzle in staging)
__device__ __forceinline__ bf16x8 lds_frag(const bf16* T, int row, int gran) {
  return *(const bf16x8*)&T[row * 64 + ((gran ^ (row & 7)) << 3)];
}

__device__ __forceinline__ f32x4 vmax4(f32x4 a, f32x4 b) {
  return f32x4{ fmaxf(a[0], b[0]), fmaxf(a[1], b[1]),
                fmaxf(a[2], b[2]), fmaxf(a[3], b[3]) };
}

// Flash attention, causal. 512 identical-work blocks: each processes q-tile
// qtA = 31-pr and qtB = pr (QBLK=64) sequentially -> 33 kv-tile iterations per
// block, 2 blocks/CU, no tail. 4 waves x 16 q-rows. Swapped QK^T (rows=kv,
// cols=q): softmax reduce is in-lane + 2 shfl.
__global__ __launch_bounds__(256) void attn_kernel(const bf16* __restrict__ qb,
                                                   const bf16* __restrict__ kb,
                                                   const bf16* __restrict__ vT,
                                                   bf16* __restrict__ ob) {
  __shared__ __attribute__((aligned(16))) bf16 Kt[2][64 * 64];
  __shared__ __attribute__((aligned(16))) bf16 Vt[2][64 * 64];
  __shared__ __attribute__((aligned(16))) bf16 Pb[4][16 * 64];
  const int w = threadIdx.x >> 6, l = threadIdx.x & 63;
  // bijective XCD chunking: 512 blocks, 64 consecutive work-items per XCD
  const int lin = blockIdx.x;
  const int swz = (lin & 7) * 64 + (lin >> 3);
  const int pr = swz & 15, h = (swz >> 4) & 15, b = swz >> 8;
  const int qtA = 31 - pr, qtB = pr;
  const int c16 = l & 15, g4 = l >> 4, r8 = l >> 3;
  const int sg = ((l & 7) ^ (r8 & 7)) * 8;  // pre-swizzled src col (elems)

  const float SC = 0.125f * 1.44269504089f;  // 1/sqrt(dk) * log2(e)

  const bf16* kbase = kb + (size_t)b * SEQ * DMODEL + h * DKH;
  const bf16* vbase = vT + (size_t)(b * NHEAD + h) * DKH * SEQ;

  // Q fragments (B-operand) for both q-tiles: row = qt*64 + w*16 + c16
  bf16x8 qfA[2], qfB[2];
#pragma unroll
  for (int d = 0; d < 2; ++d) {
    qfA[d] = *(const bf16x8*)(qb + (size_t)(b * SEQ + qtA * 64 + w * 16 + c16) * DMODEL +
                              h * DKH + d * 32 + g4 * 8);
    qfB[d] = *(const bf16x8*)(qb + (size_t)(b * SEQ + qtB * 64 + w * 16 + c16) * DMODEL +
                              h * DKH + d * 32 + g4 * 8);
  }

  auto stage = [&](int buf, int t) {
    const int kt0 = t * 64;
#pragma unroll
    for (int c = 0; c < 2; ++c) {
      const int row = w * 16 + c * 8;  // wave-uniform segment base
      gl_lds16(kbase + (size_t)(kt0 + row + r8) * DMODEL + sg, &Kt[buf][row * 64]);
      gl_lds16(vbase + (size_t)(row + r8) * SEQ + kt0 + sg, &Vt[buf][row * 64]);
    }
  };

  stage(0, 0);
  __syncthreads();

  float mm = -INFINITY, ll = 0.f;
  f32x4 acc[4];
#pragma unroll
  for (int n = 0; n < 4; ++n) acc[n] = f32x4{0.f, 0.f, 0.f, 0.f};

  const int TA = qtA + 1, TT = TA + qtB + 1;
  const int ql = w * 16 + c16;  // q row local to tile (for diagonal mask)

  for (int tt = 0; tt < TT; ++tt) {
    const int cur = tt & 1;
    if (tt + 1 < TT) stage(cur ^ 1, (tt + 1 < TA) ? tt + 1 : tt + 1 - TA);
    const bool pA = tt < TA;
    const int t_in = pA ? tt : tt - TA;
    const bool diag = (t_in == (pA ? qtA : qtB));
    const bf16x8 q0 = pA ? qfA[0] : qfB[0];
    const bf16x8 q1 = pA ? qfA[1] : qfB[1];

    // ---- QK^T swapped: s[j] rows kv = j*16+g4*4+r, cols q = c16
    f32x4 s[4];
    __builtin_amdgcn_s_setprio(1);
#pragma unroll
    for (int j = 0; j < 4; ++j) {
      bf16x8 kf0 = lds_frag(Kt[cur], j * 16 + c16, g4);
      bf16x8 kf1 = lds_frag(Kt[cur], j * 16 + c16, 4 + g4);
      f32x4 c = f32x4{0.f, 0.f, 0.f, 0.f};
      c = __builtin_amdgcn_mfma_f32_16x16x32_bf16(kf0, q0, c, 0, 0, 0);
      c = __builtin_amdgcn_mfma_f32_16x16x32_bf16(kf1, q1, c, 0, 0, 0);
      s[j] = c * SC;
    }
    __builtin_amdgcn_s_setprio(0);
    if (diag) {
#pragma unroll
      for (int j = 0; j < 4; ++j)
#pragma unroll
        for (int r = 0; r < 4; ++r)
          if (j * 16 + g4 * 4 + r > ql) s[j][r] = -INFINITY;
    }
    // ---- online softmax: 16 scores of q-row ql in-lane
    f32x4 t01 = vmax4(s[0], s[1]);
    f32x4 t23 = vmax4(s[2], s[3]);
    f32x4 tv = vmax4(t01, t23);
    float v = fmaxf(fmaxf(tv[0], tv[1]), fmaxf(tv[2], tv[3]));
    v = fmaxf(v, __shfl_xor(v, 16));
    v = fmaxf(v, __shfl_xor(v, 32));
    const float mn = fmaxf(mm, v);
    const float scl = __builtin_amdgcn_exp2f(mm - mn);
    f32x4 ps = f32x4{0.f, 0.f, 0.f, 0.f};
#pragma unroll
    for (int j = 0; j < 4; ++j)
#pragma unroll
      for (int r = 0; r < 4; ++r) {
        float p = __builtin_amdgcn_exp2f(s[j][r] - mn);
        s[j][r] = p;
        ps[r] += p;
      }
    float rs = (ps[0] + ps[1]) + (ps[2] + ps[3]);
    rs += __shfl_xor(rs, 16);
    rs += __shfl_xor(rs, 32);
    ll = ll * scl + rs;
    mm = mn;
    // ---- spill P: lane's 4 consecutive kv (r=0..3) -> one b64 store
    bf16* P = &Pb[w][0];
#pragma unroll
    for (int j = 0; j < 4; ++j) {
      const int col = j * 16 + g4 * 4;
      bf16x4 pk = { (bf16)s[j][0], (bf16)s[j][1], (bf16)s[j][2], (bf16)s[j][3] };
      *(bf16x4*)&P[c16 * 64 + (((col >> 3) ^ (c16 & 7)) << 3) + (col & 7)] = pk;
    }
    // ---- redistribute rescale factor to acc layout (q = g4*4+r)
    float sc4[4];
#pragma unroll
    for (int r = 0; r < 4; ++r) sc4[r] = __shfl(scl, g4 * 4 + r);
#pragma unroll
    for (int n = 0; n < 4; ++n)
#pragma unroll
      for (int r = 0; r < 4; ++r) acc[n][r] *= sc4[r];
    // ---- PV: A = P rows q, B = V rows dk
    bf16x8 pa0 = lds_frag(P, c16, g4);
    bf16x8 pa1 = lds_frag(P, c16, 4 + g4);
    __builtin_amdgcn_s_setprio(1);
#pragma unroll
    for (int n = 0; n < 4; ++n) {
      bf16x8 vf0 = lds_frag(Vt[cur], n * 16 + c16, g4);
      bf16x8 vf1 = lds_frag(Vt[cur], n * 16 + c16, 4 + g4);
      acc[n] = __builtin_amdgcn_mfma_f32_16x16x32_bf16(pa0, vf0, acc[n], 0, 0, 0);
      acc[n] = __builtin_amdgcn_mfma_f32_16x16x32_bf16(pa1, vf1, acc[n], 0, 0, 0);
    }
    __builtin_amdgcn_s_setprio(0);

    if (tt == TA - 1) {  // finish q-tile A, reset state for B
      float ls[4];
#pragma unroll
      for (int r = 0; r < 4; ++r) ls[r] = __shfl(ll, g4 * 4 + r);
#pragma unroll
      for (int n = 0; n < 4; ++n)
#pragma unroll
        for (int r = 0; r < 4; ++r) {
          float o = acc[n][r] / ls[r];
          ob[(size_t)(b * SEQ + qtA * 64 + w * 16 + g4 * 4 + r) * DMODEL +
             h * DKH + n * 16 + c16] = (bf16)o;
          acc[n][r] = 0.f;
        }
      mm = -INFINITY;
      ll = 0.f;
    }
    __syncthreads();
  }

  // epilogue for q-tile B
  float ls[4];
#pragma unroll
  for (int r = 0; r < 4; ++r) ls[r] = __shfl(ll, g4 * 4 + r);
#pragma unroll
  for (int n = 0; n < 4; ++n)
#pragma unroll
    for (int r = 0; r < 4; ++r) {
      float o = acc[n][r] / ls[r];
      ob[(size_t)(b * SEQ + qtB * 64 + w * 16 + g4 * 4 + r) * DMODEL +
         h * DKH + n * 16 + c16] = (bf16)o;
    }
}

extern "C" void kernel_launch(void* const* d_in, const int* in_sizes, int n_in,
                              void* d_out, int out_size, void* d_ws, size_t ws_size,
                              hipStream_t stream) {
  const float* x  = (const float*)d_in[0];
  const float* Wq = (const float*)d_in[1];
  const float* Wk = (const float*)d_in[2];
  const float* Wv = (const float*)d_in[3];
  const float* Wo = (const float*)d_in[4];
  float* out = (float*)d_out;
  char* ws = (char*)d_ws;
  const size_t MB = (size_t)1 << 20;

  // wqb/wkb/wvb contiguous -> one [3072][1024] weight matrix for fused QKV
  bf16* xb   = (bf16*)(ws + 0 * MB);   // 8MB
  bf16* wqb  = (bf16*)(ws + 8 * MB);   // 2MB
  bf16* wkb  = (bf16*)(ws + 10 * MB);  // 2MB
  bf16* wvb  = (bf16*)(ws + 12 * MB);  // 2MB
  bf16* wob  = (bf16*)(ws + 14 * MB);  // 2MB
  bf16* qbuf = (bf16*)(ws + 16 * MB);  // 8MB
  bf16* kbuf = (bf16*)(ws + 24 * MB);  // 8MB
  bf16* vTb  = (bf16*)(ws + 32 * MB);  // 8MB, [b][h][dk][s]
  bf16* abuf = (bf16*)(ws + 40 * MB);  // 8MB

  cvt5_kernel<<<8192, 256, 0, stream>>>(x, Wq, Wk, Wv, Wo, xb, wqb, wkb, wvb, wob);

  // fused QKV projection: N = 3072, 768 blocks (~3/CU)
  gemm_nt<3><<<dim3(3072 / 128, 4096 / 128), 256, 0, stream>>>(
      xb, wqb, nullptr, qbuf, kbuf, vTb, 4096, 3072, 1024);

  attn_kernel<<<dim3(512), 256, 0, stream>>>(qbuf, kbuf, vTb, abuf);

  gemm_nt<0><<<dim3(1024 / 128, 4096 / 128), 256, 0, stream>>>(
      abuf, wob, out, nullptr, nullptr, nullptr, 4096, 1024, 1024);
}

// Round 6
// 181.789 us; speedup vs baseline: 2.3140x; 1.0719x over previous
//
#include <hip/hip_runtime.h>
#include <hip/hip_bf16.h>
#include <math.h>

typedef __bf16 bf16;
typedef __attribute__((ext_vector_type(8))) __bf16 bf16x8;
typedef __attribute__((ext_vector_type(4))) __bf16 bf16x4;
typedef __attribute__((ext_vector_type(4))) float f32x4;

#define NHEAD 16
#define DKH 64
#define SEQ 2048
#define DMODEL 1024

// async 16B global->LDS (wave-uniform LDS base + lane*16, per-lane global src)
__device__ __forceinline__ void gl_lds16(const void* g, void* lds) {
  __builtin_amdgcn_global_load_lds(
      (const __attribute__((address_space(1))) unsigned int*)g,
      (__attribute__((address_space(3))) unsigned int*)lds, 16, 0, 0);
}

// one launch converting x + 4 weight matrices fp32->bf16 (4-elem units)
__global__ void cvt5_kernel(const float* __restrict__ x, const float* __restrict__ wq,
                            const float* __restrict__ wk, const float* __restrict__ wv,
                            const float* __restrict__ wo, bf16* __restrict__ xb,
                            bf16* __restrict__ wqb, bf16* __restrict__ wkb,
                            bf16* __restrict__ wvb, bf16* __restrict__ wob) {
  int i = blockIdx.x * blockDim.x + threadIdx.x;  // [0, 2097152)
  const float* src; bf16* dst; int li;
  if (i < 1048576)      { src = x;  dst = xb;  li = i; }
  else if (i < 1310720) { src = wq; dst = wqb; li = i - 1048576; }
  else if (i < 1572864) { src = wk; dst = wkb; li = i - 1310720; }
  else if (i < 1835008) { src = wv; dst = wvb; li = i - 1572864; }
  else                  { src = wo; dst = wob; li = i - 1835008; }
  float4 v = ((const float4*)src)[li];
  bf16x4 o = { (bf16)v.x, (bf16)v.y, (bf16)v.z, (bf16)v.w };
  ((bf16x4*)dst)[li] = o;
}

// swizzled LDS fragment read: tile is [rows][64 cols] bf16, 8-elem granules,
// granule ^= (row&7) (matches the source-side pre-swizzle in staging)
__device__ __forceinline__ bf16x8 lds_frag(const bf16* T, int row, int gran) {
  return *(const bf16x8*)&T[row * 64 + ((gran ^ (row & 7)) << 3)];
}

// C[m,n] = sum_k A[m,k]*B[n,k]; A:[M,K], B:[N,K] bf16 row-major. BK=64,
// swizzled LDS (conflict-free ds_read_b128). MODE 0: fp32 C -> Cf.
// MODE 3: fused QKV: col<1024 -> Cq, <2048 -> Ck, else Cv transposed per head.
template<int MODE>
__global__ __launch_bounds__(256) void gemm_nt(const bf16* __restrict__ A,
                                               const bf16* __restrict__ Bw,
                                               float* __restrict__ Cf,
                                               bf16* __restrict__ Cq,
                                               bf16* __restrict__ Ck,
                                               bf16* __restrict__ Cv,
                                               int M, int N, int K) {
  __shared__ __attribute__((aligned(16))) bf16 As[128 * 64];
  __shared__ __attribute__((aligned(16))) bf16 Bs[128 * 64];
  const int t = threadIdx.x;
  const int w = t >> 6, l = t & 63;
  const int wr = w >> 1, wc = w & 1;
  // XCD-chunked swizzle (nwg divisible by 8): contiguous tile chunk per XCD
  const int lin = blockIdx.y * gridDim.x + blockIdx.x;
  const int cpx = (gridDim.x * gridDim.y) >> 3;
  const int swz = (lin & 7) * cpx + (lin >> 3);
  const int tm = (swz / gridDim.x) * 128, tn = (swz % gridDim.x) * 128;
  const int c16 = l & 15, g4 = l >> 4, r8 = l >> 3;
  const int sg = ((l & 7) ^ (r8 & 7)) * 8;  // pre-swizzled src col (elems)

  f32x4 acc[4][4];
#pragma unroll
  for (int i = 0; i < 4; ++i)
#pragma unroll
    for (int j = 0; j < 4; ++j) acc[i][j] = f32x4{0.f, 0.f, 0.f, 0.f};

  for (int k0 = 0; k0 < K; k0 += 64) {
#pragma unroll
    for (int c = 0; c < 4; ++c) {
      const int r0 = w * 32 + c * 8;  // wave-uniform segment base (8 rows)
      gl_lds16(A + (size_t)(tm + r0 + r8) * K + k0 + sg, &As[r0 * 64]);
      gl_lds16(Bw + (size_t)(tn + r0 + r8) * K + k0 + sg, &Bs[r0 * 64]);
    }
    __syncthreads();
#pragma unroll
    for (int h = 0; h < 2; ++h) {  // two K=32 halves of the BK=64 tile
      bf16x8 af[4], bfr[4];
#pragma unroll
      for (int i = 0; i < 4; ++i)
        af[i] = lds_frag(As, wr * 64 + i * 16 + c16, h * 4 + g4);
#pragma unroll
      for (int j = 0; j < 4; ++j)
        bfr[j] = lds_frag(Bs, wc * 64 + j * 16 + c16, h * 4 + g4);
#pragma unroll
      for (int i = 0; i < 4; ++i)
#pragma unroll
        for (int j = 0; j < 4; ++j)
          acc[i][j] = __builtin_amdgcn_mfma_f32_16x16x32_bf16(af[i], bfr[j], acc[i][j], 0, 0, 0);
    }
    __syncthreads();
  }

  const int which = tn >> 10;  // MODE 3: whole block in one of q/k/v
#pragma unroll
  for (int i = 0; i < 4; ++i) {
    const int row0 = tm + wr * 64 + i * 16 + g4 * 4;
#pragma unroll
    for (int j = 0; j < 4; ++j) {
      const int col = tn + wc * 64 + j * 16 + c16;
      if (MODE == 0) {
#pragma unroll
        for (int r = 0; r < 4; ++r) Cf[(size_t)(row0 + r) * N + col] = acc[i][j][r];
      } else {
        const int lc = col & 1023;
        if (which == 2) {  // V: transposed per head
          const int bb = row0 >> 11, s = row0 & 2047;
          const int hh = lc >> 6, dk = lc & 63;
          bf16x4 o = { (bf16)acc[i][j][0], (bf16)acc[i][j][1],
                       (bf16)acc[i][j][2], (bf16)acc[i][j][3] };
          *(bf16x4*)&Cv[((size_t)(bb * NHEAD + hh) * DKH + dk) * SEQ + s] = o;
        } else {
          bf16* dst = which ? Ck : Cq;
#pragma unroll
          for (int r = 0; r < 4; ++r)
            dst[(size_t)(row0 + r) * DMODEL + lc] = (bf16)acc[i][j][r];
        }
      }
    }
  }
}

__device__ __forceinline__ f32x4 vmax4(f32x4 a, f32x4 b) {
  return f32x4{ fmaxf(a[0], b[0]), fmaxf(a[1], b[1]),
                fmaxf(a[2], b[2]), fmaxf(a[3], b[3]) };
}

// Flash attention, causal. 512 identical-work blocks: each processes q-tile
// qtA = 31-pr then qtB = pr (QBLK=64) -> 33 kv-tile iterations per block.
// Swapped QK^T (rows=kv, cols=q): softmax reduce in-lane + 2 shfl. Row-sum
// via MFMA with ones-B (l lands in acc layout). Defer-max (T13, THR=8 in
// exp2-space) skips the rescale pass on most tiles.
__global__ __launch_bounds__(256) void attn_kernel(const bf16* __restrict__ qb,
                                                   const bf16* __restrict__ kb,
                                                   const bf16* __restrict__ vT,
                                                   bf16* __restrict__ ob) {
  __shared__ __attribute__((aligned(16))) bf16 Kt[2][64 * 64];
  __shared__ __attribute__((aligned(16))) bf16 Vt[2][64 * 64];
  __shared__ __attribute__((aligned(16))) bf16 Pb[4][16 * 64];
  const int w = threadIdx.x >> 6, l = threadIdx.x & 63;
  // bijective XCD chunking: 512 blocks, 64 consecutive work-items per XCD
  const int lin = blockIdx.x;
  const int swz = (lin & 7) * 64 + (lin >> 3);
  const int pr = swz & 15, h = (swz >> 4) & 15, b = swz >> 8;
  const int qtA = 31 - pr, qtB = pr;
  const int c16 = l & 15, g4 = l >> 4, r8 = l >> 3;
  const int sg = ((l & 7) ^ (r8 & 7)) * 8;  // pre-swizzled src col (elems)

  const float SC2 = 0.125f * 1.44269504089f;  // 1/sqrt(dk) * log2(e)
  const float THR = 8.0f / SC2;               // defer-max threshold (raw scores)

  const bf16 oneb = (bf16)1.0f;
  const bf16x8 ones = { oneb, oneb, oneb, oneb, oneb, oneb, oneb, oneb };

  const bf16* kbase = kb + (size_t)b * SEQ * DMODEL + h * DKH;
  const bf16* vbase = vT + (size_t)(b * NHEAD + h) * DKH * SEQ;

  // Q fragments (B-operand) for both q-tiles: row = qt*64 + w*16 + c16
  bf16x8 qfA[2], qfB[2];
#pragma unroll
  for (int d = 0; d < 2; ++d) {
    qfA[d] = *(const bf16x8*)(qb + (size_t)(b * SEQ + qtA * 64 + w * 16 + c16) * DMODEL +
                              h * DKH + d * 32 + g4 * 8);
    qfB[d] = *(const bf16x8*)(qb + (size_t)(b * SEQ + qtB * 64 + w * 16 + c16) * DMODEL +
                              h * DKH + d * 32 + g4 * 8);
  }

  auto stage = [&](int buf, int t) {
    const int kt0 = t * 64;
#pragma unroll
    for (int c = 0; c < 2; ++c) {
      const int row = w * 16 + c * 8;  // wave-uniform segment base
      gl_lds16(kbase + (size_t)(kt0 + row + r8) * DMODEL + sg, &Kt[buf][row * 64]);
      gl_lds16(vbase + (size_t)(row + r8) * SEQ + kt0 + sg, &Vt[buf][row * 64]);
    }
  };

  stage(0, 0);
  __syncthreads();

  float mm = -INFINITY;
  f32x4 lsum4 = f32x4{0.f, 0.f, 0.f, 0.f};
  f32x4 acc[4];
#pragma unroll
  for (int n = 0; n < 4; ++n) acc[n] = f32x4{0.f, 0.f, 0.f, 0.f};

  const int TA = qtA + 1, TT = TA + qtB + 1;
  const int ql = w * 16 + c16;  // q row local to tile (for diagonal mask)

  for (int tt = 0; tt < TT; ++tt) {
    const int cur = tt & 1;
    if (tt + 1 < TT) stage(cur ^ 1, (tt + 1 < TA) ? tt + 1 : tt + 1 - TA);
    const bool pA = tt < TA;
    const int t_in = pA ? tt : tt - TA;
    const bool diag = (t_in == (pA ? qtA : qtB));
    const bf16x8 q0 = pA ? qfA[0] : qfB[0];
    const bf16x8 q1 = pA ? qfA[1] : qfB[1];

    // ---- QK^T swapped (raw scores): s[j] rows kv = j*16+g4*4+r, cols q = c16
    f32x4 s[4];
    __builtin_amdgcn_s_setprio(1);
#pragma unroll
    for (int j = 0; j < 4; ++j) {
      bf16x8 kf0 = lds_frag(Kt[cur], j * 16 + c16, g4);
      bf16x8 kf1 = lds_frag(Kt[cur], j * 16 + c16, 4 + g4);
      f32x4 c = f32x4{0.f, 0.f, 0.f, 0.f};
      c = __builtin_amdgcn_mfma_f32_16x16x32_bf16(kf0, q0, c, 0, 0, 0);
      c = __builtin_amdgcn_mfma_f32_16x16x32_bf16(kf1, q1, c, 0, 0, 0);
      s[j] = c;
    }
    __builtin_amdgcn_s_setprio(0);
    if (diag) {
#pragma unroll
      for (int j = 0; j < 4; ++j)
#pragma unroll
        for (int r = 0; r < 4; ++r)
          if (j * 16 + g4 * 4 + r > ql) s[j][r] = -INFINITY;
    }
    // ---- tile max of the 16 in-lane scores + 2 shfl
    f32x4 t01 = vmax4(s[0], s[1]);
    f32x4 t23 = vmax4(s[2], s[3]);
    f32x4 tv = vmax4(t01, t23);
    float v = fmaxf(fmaxf(tv[0], tv[1]), fmaxf(tv[2], tv[3]));
    v = fmaxf(v, __shfl_xor(v, 16));
    v = fmaxf(v, __shfl_xor(v, 32));
    // ---- defer-max: skip rescale when bounded (p <= 2^8)
    if (!__all(v <= mm + THR)) {
      const float mn = fmaxf(mm, v);
      const float scl = __builtin_amdgcn_exp2f(SC2 * (mm - mn));  // 0 on first tile
      float sc4[4];
#pragma unroll
      for (int r = 0; r < 4; ++r) sc4[r] = __shfl(scl, g4 * 4 + r);
#pragma unroll
      for (int n = 0; n < 4; ++n)
#pragma unroll
        for (int r = 0; r < 4; ++r) acc[n][r] *= sc4[r];
#pragma unroll
      for (int r = 0; r < 4; ++r) lsum4[r] *= sc4[r];
      mm = mn;
    }
    const float nb = SC2 * mm;
    // ---- exp + spill P: lane's 4 consecutive kv (r=0..3) -> one b64 store
    bf16* P = &Pb[w][0];
#pragma unroll
    for (int j = 0; j < 4; ++j) {
      bf16x4 pk;
#pragma unroll
      for (int r = 0; r < 4; ++r)
        pk[r] = (bf16)__builtin_amdgcn_exp2f(fmaf(s[j][r], SC2, -nb));
      const int col = j * 16 + g4 * 4;
      *(bf16x4*)&P[c16 * 64 + (((col >> 3) ^ (c16 & 7)) << 3) + (col & 7)] = pk;
    }
    // ---- PV + row-sum: A = P rows q; B = V rows dk / ones
    bf16x8 pa0 = lds_frag(P, c16, g4);
    bf16x8 pa1 = lds_frag(P, c16, 4 + g4);
    __builtin_amdgcn_s_setprio(1);
#pragma unroll
    for (int n = 0; n < 4; ++n) {
      bf16x8 vf0 = lds_frag(Vt[cur], n * 16 + c16, g4);
      bf16x8 vf1 = lds_frag(Vt[cur], n * 16 + c16, 4 + g4);
      acc[n] = __builtin_amdgcn_mfma_f32_16x16x32_bf16(pa0, vf0, acc[n], 0, 0, 0);
      acc[n] = __builtin_amdgcn_mfma_f32_16x16x32_bf16(pa1, vf1, acc[n], 0, 0, 0);
    }
    lsum4 = __builtin_amdgcn_mfma_f32_16x16x32_bf16(pa0, ones, lsum4, 0, 0, 0);
    lsum4 = __builtin_amdgcn_mfma_f32_16x16x32_bf16(pa1, ones, lsum4, 0, 0, 0);
    __builtin_amdgcn_s_setprio(0);

    if (tt == TA - 1) {  // finish q-tile A, reset state for B
#pragma unroll
      for (int n = 0; n < 4; ++n)
#pragma unroll
        for (int r = 0; r < 4; ++r) {
          float o = acc[n][r] / lsum4[r];
          ob[(size_t)(b * SEQ + qtA * 64 + w * 16 + g4 * 4 + r) * DMODEL +
             h * DKH + n * 16 + c16] = (bf16)o;
          acc[n][r] = 0.f;
        }
      lsum4 = f32x4{0.f, 0.f, 0.f, 0.f};
      mm = -INFINITY;
    }
    __syncthreads();
  }

  // epilogue for q-tile B
#pragma unroll
  for (int n = 0; n < 4; ++n)
#pragma unroll
    for (int r = 0; r < 4; ++r) {
      float o = acc[n][r] / lsum4[r];
      ob[(size_t)(b * SEQ + qtB * 64 + w * 16 + g4 * 4 + r) * DMODEL +
         h * DKH + n * 16 + c16] = (bf16)o;
    }
}

extern "C" void kernel_launch(void* const* d_in, const int* in_sizes, int n_in,
                              void* d_out, int out_size, void* d_ws, size_t ws_size,
                              hipStream_t stream) {
  const float* x  = (const float*)d_in[0];
  const float* Wq = (const float*)d_in[1];
  const float* Wk = (const float*)d_in[2];
  const float* Wv = (const float*)d_in[3];
  const float* Wo = (const float*)d_in[4];
  float* out = (float*)d_out;
  char* ws = (char*)d_ws;
  const size_t MB = (size_t)1 << 20;

  // wqb/wkb/wvb contiguous -> one [3072][1024] weight matrix for fused QKV
  bf16* xb   = (bf16*)(ws + 0 * MB);   // 8MB
  bf16* wqb  = (bf16*)(ws + 8 * MB);   // 2MB
  bf16* wkb  = (bf16*)(ws + 10 * MB);  // 2MB
  bf16* wvb  = (bf16*)(ws + 12 * MB);  // 2MB
  bf16* wob  = (bf16*)(ws + 14 * MB);  // 2MB
  bf16* qbuf = (bf16*)(ws + 16 * MB);  // 8MB
  bf16* kbuf = (bf16*)(ws + 24 * MB);  // 8MB
  bf16* vTb  = (bf16*)(ws + 32 * MB);  // 8MB, [b][h][dk][s]
  bf16* abuf = (bf16*)(ws + 40 * MB);  // 8MB

  cvt5_kernel<<<8192, 256, 0, stream>>>(x, Wq, Wk, Wv, Wo, xb, wqb, wkb, wvb, wob);

  // fused QKV projection: N = 3072, 768 blocks (~3/CU)
  gemm_nt<3><<<dim3(3072 / 128, 4096 / 128), 256, 0, stream>>>(
      xb, wqb, nullptr, qbuf, kbuf, vTb, 4096, 3072, 1024);

  attn_kernel<<<dim3(512), 256, 0, stream>>>(qbuf, kbuf, vTb, abuf);

  gemm_nt<0><<<dim3(1024 / 128, 4096 / 128), 256, 0, stream>>>(
      abuf, wob, out, nullptr, nullptr, nullptr, 4096, 1024, 1024);
}

// Round 7
// 181.419 us; speedup vs baseline: 2.3188x; 1.0020x over previous
//
#include <hip/hip_runtime.h>
#include <hip/hip_bf16.h>
#include <math.h>

typedef __bf16 bf16;
typedef __attribute__((ext_vector_type(8))) __bf16 bf16x8;
typedef __attribute__((ext_vector_type(4))) __bf16 bf16x4;
typedef __attribute__((ext_vector_type(4))) float f32x4;

#define NHEAD 16
#define DKH 64
#define SEQ 2048
#define DMODEL 1024

// async 16B global->LDS (wave-uniform LDS base + lane*16, per-lane global src)
__device__ __forceinline__ void gl_lds16(const void* g, void* lds) {
  __builtin_amdgcn_global_load_lds(
      (const __attribute__((address_space(1))) unsigned int*)g,
      (__attribute__((address_space(3))) unsigned int*)lds, 16, 0, 0);
}

// one launch converting x + 4 weight matrices fp32->bf16 (4-elem units)
__global__ void cvt5_kernel(const float* __restrict__ x, const float* __restrict__ wq,
                            const float* __restrict__ wk, const float* __restrict__ wv,
                            const float* __restrict__ wo, bf16* __restrict__ xb,
                            bf16* __restrict__ wqb, bf16* __restrict__ wkb,
                            bf16* __restrict__ wvb, bf16* __restrict__ wob) {
  int i = blockIdx.x * blockDim.x + threadIdx.x;  // [0, 2097152)
  const float* src; bf16* dst; int li;
  if (i < 1048576)      { src = x;  dst = xb;  li = i; }
  else if (i < 1310720) { src = wq; dst = wqb; li = i - 1048576; }
  else if (i < 1572864) { src = wk; dst = wkb; li = i - 1310720; }
  else if (i < 1835008) { src = wv; dst = wvb; li = i - 1572864; }
  else                  { src = wo; dst = wob; li = i - 1835008; }
  float4 v = ((const float4*)src)[li];
  bf16x4 o = { (bf16)v.x, (bf16)v.y, (bf16)v.z, (bf16)v.w };
  ((bf16x4*)dst)[li] = o;
}

// swizzled LDS fragment read: tile is [rows][64 cols] bf16, 8-elem granules,
// granule ^= (row&7) (matches the source-side pre-swizzle in staging)
__device__ __forceinline__ bf16x8 lds_frag(const bf16* T, int row, int gran) {
  return *(const bf16x8*)&T[row * 64 + ((gran ^ (row & 7)) << 3)];
}

// C[m,n] = sum_k A[m,k]*B[n,k]; A:[M,K], B:[N,K] bf16 row-major. BK=64,
// swizzled LDS, DOUBLE-BUFFERED 2-phase: stage(next) -> compute(cur) -> one
// barrier (T3 minimum recipe). MODE 0: fp32 C. MODE 3: fused QKV split.
template<int MODE>
__global__ __launch_bounds__(256) void gemm_nt(const bf16* __restrict__ A,
                                               const bf16* __restrict__ Bw,
                                               float* __restrict__ Cf,
                                               bf16* __restrict__ Cq,
                                               bf16* __restrict__ Ck,
                                               bf16* __restrict__ Cv,
                                               int M, int N, int K) {
  __shared__ __attribute__((aligned(16))) bf16 As[2][128 * 64];
  __shared__ __attribute__((aligned(16))) bf16 Bs[2][128 * 64];
  const int t = threadIdx.x;
  const int w = t >> 6, l = t & 63;
  const int wr = w >> 1, wc = w & 1;
  // XCD-chunked swizzle (nwg divisible by 8): contiguous tile chunk per XCD
  const int lin = blockIdx.y * gridDim.x + blockIdx.x;
  const int cpx = (gridDim.x * gridDim.y) >> 3;
  const int swz = (lin & 7) * cpx + (lin >> 3);
  const int tm = (swz / gridDim.x) * 128, tn = (swz % gridDim.x) * 128;
  const int c16 = l & 15, g4 = l >> 4, r8 = l >> 3;
  const int sg = ((l & 7) ^ (r8 & 7)) * 8;  // pre-swizzled src col (elems)

  f32x4 acc[4][4];
#pragma unroll
  for (int i = 0; i < 4; ++i)
#pragma unroll
    for (int j = 0; j < 4; ++j) acc[i][j] = f32x4{0.f, 0.f, 0.f, 0.f};

  auto stage = [&](int buf, int k0) {
#pragma unroll
    for (int c = 0; c < 4; ++c) {
      const int r0 = w * 32 + c * 8;  // wave-uniform segment base (8 rows)
      gl_lds16(A + (size_t)(tm + r0 + r8) * K + k0 + sg, &As[buf][r0 * 64]);
      gl_lds16(Bw + (size_t)(tn + r0 + r8) * K + k0 + sg, &Bs[buf][r0 * 64]);
    }
  };

  const int NK = K >> 6;
  stage(0, 0);
  __syncthreads();

  for (int kt = 0; kt < NK; ++kt) {
    const int cur = kt & 1;
    if (kt + 1 < NK) stage(cur ^ 1, (kt + 1) << 6);
#pragma unroll
    for (int hh = 0; hh < 2; ++hh) {  // two K=32 halves of the BK=64 tile
      bf16x8 af[4], bfr[4];
#pragma unroll
      for (int i = 0; i < 4; ++i)
        af[i] = lds_frag(As[cur], wr * 64 + i * 16 + c16, hh * 4 + g4);
#pragma unroll
      for (int j = 0; j < 4; ++j)
        bfr[j] = lds_frag(Bs[cur], wc * 64 + j * 16 + c16, hh * 4 + g4);
#pragma unroll
      for (int i = 0; i < 4; ++i)
#pragma unroll
        for (int j = 0; j < 4; ++j)
          acc[i][j] = __builtin_amdgcn_mfma_f32_16x16x32_bf16(af[i], bfr[j], acc[i][j], 0, 0, 0);
    }
    __syncthreads();  // drains prefetch vmcnt + everyone done reading cur
  }

  const int which = tn >> 10;  // MODE 3: whole block in one of q/k/v
#pragma unroll
  for (int i = 0; i < 4; ++i) {
    const int row0 = tm + wr * 64 + i * 16 + g4 * 4;
#pragma unroll
    for (int j = 0; j < 4; ++j) {
      const int col = tn + wc * 64 + j * 16 + c16;
      if (MODE == 0) {
#pragma unroll
        for (int r = 0; r < 4; ++r) Cf[(size_t)(row0 + r) * N + col] = acc[i][j][r];
      } else {
        const int lc = col & 1023;
        if (which == 2) {  // V: transposed per head
          const int bb = row0 >> 11, s = row0 & 2047;
          const int hh = lc >> 6, dk = lc & 63;
          bf16x4 o = { (bf16)acc[i][j][0], (bf16)acc[i][j][1],
                       (bf16)acc[i][j][2], (bf16)acc[i][j][3] };
          *(bf16x4*)&Cv[((size_t)(bb * NHEAD + hh) * DKH + dk) * SEQ + s] = o;
        } else {
          bf16* dst = which ? Ck : Cq;
#pragma unroll
          for (int r = 0; r < 4; ++r)
            dst[(size_t)(row0 + r) * DMODEL + lc] = (bf16)acc[i][j][r];
        }
      }
    }
  }
}

__device__ __forceinline__ f32x4 vmax4(f32x4 a, f32x4 b) {
  return f32x4{ fmaxf(a[0], b[0]), fmaxf(a[1], b[1]),
                fmaxf(a[2], b[2]), fmaxf(a[3], b[3]) };
}

// Flash attention, causal. 512 blocks x 512 threads (8 waves). Waves split in
// two groups: A (w<4) handles even 64-kv subtiles, B odd, of a staged 128-kv
// tile. Each block: q-tile pair (31-pr, pr) -> uniformly 17 iterations.
// Per-q-tile merge of (m,l,acc) through LDS (B -> A). Swapped QK^T, in-lane
// softmax, MFMA row-sum, defer-max.
__global__ __launch_bounds__(512, 4) void attn_kernel(const bf16* __restrict__ qb,
                                                      const bf16* __restrict__ kb,
                                                      const bf16* __restrict__ vT,
                                                      bf16* __restrict__ ob) {
  __shared__ __attribute__((aligned(16))) bf16 Ke[2][64 * 64];
  __shared__ __attribute__((aligned(16))) bf16 Ko[2][64 * 64];
  __shared__ __attribute__((aligned(16))) bf16 Ve[2][64 * 64];
  __shared__ __attribute__((aligned(16))) bf16 Vo[2][64 * 64];
  __shared__ __attribute__((aligned(16))) bf16 Pb[8][16 * 64];  // P + merge area
  const int w = threadIdx.x >> 6, l = threadIdx.x & 63;
  const int g = w >> 2, wq = w & 3;
  // bijective XCD chunking: 512 blocks, 64 consecutive work-items per XCD
  const int lin = blockIdx.x;
  const int swz = (lin & 7) * 64 + (lin >> 3);
  const int pr = swz & 15, h = (swz >> 4) & 15, b = swz >> 8;
  const int qtA = 31 - pr, qtB = pr;
  const int c16 = l & 15, g4 = l >> 4, r8 = l >> 3;
  const int sg = ((l & 7) ^ (r8 & 7)) * 8;  // pre-swizzled src col (elems)

  const float SC2 = 0.125f * 1.44269504089f;  // 1/sqrt(dk) * log2(e)
  const float THR = 8.0f / SC2;               // defer-max threshold (raw scores)

  const bf16 oneb = (bf16)1.0f;
  const bf16x8 ones = { oneb, oneb, oneb, oneb, oneb, oneb, oneb, oneb };

  const bf16* kbase = kb + (size_t)b * SEQ * DMODEL + h * DKH;
  const bf16* vbase = vT + (size_t)(b * NHEAD + h) * DKH * SEQ;

  // Q fragments (B-operand) for both q-tiles: row = qt*64 + wq*16 + c16
  bf16x8 qfA[2], qfB[2];
#pragma unroll
  for (int d = 0; d < 2; ++d) {
    qfA[d] = *(const bf16x8*)(qb + (size_t)(b * SEQ + qtA * 64 + wq * 16 + c16) * DMODEL +
                              h * DKH + d * 32 + g4 * 8);
    qfB[d] = *(const bf16x8*)(qb + (size_t)(b * SEQ + qtB * 64 + wq * 16 + c16) * DMODEL +
                              h * DKH + d * 32 + g4 * 8);
  }

  // stage a 128-kv tile (t128): 4 regions of 64x64, each wave does 8 rows each
  auto stage = [&](int buf, int t128) {
    const int kt0 = t128 * 128;
    const int row = w * 8;  // wave-uniform segment base
    gl_lds16(kbase + (size_t)(kt0 + row + r8) * DMODEL + sg, &Ke[buf][row * 64]);
    gl_lds16(kbase + (size_t)(kt0 + 64 + row + r8) * DMODEL + sg, &Ko[buf][row * 64]);
    gl_lds16(vbase + (size_t)(row + r8) * SEQ + kt0 + sg, &Ve[buf][row * 64]);
    gl_lds16(vbase + (size_t)(row + r8) * SEQ + kt0 + 64 + sg, &Vo[buf][row * 64]);
  };

  stage(0, 0);
  __syncthreads();

  float mm = -INFINITY;
  f32x4 lsum4 = f32x4{0.f, 0.f, 0.f, 0.f};
  f32x4 acc[4];
#pragma unroll
  for (int n = 0; n < 4; ++n) acc[n] = f32x4{0.f, 0.f, 0.f, 0.f};

  const int TA128 = (qtA + 2) >> 1;           // ceil((qtA+1)/2)
  const int TT128 = TA128 + ((qtB + 2) >> 1); // uniformly 17
  const int ql = wq * 16 + c16;               // q row local to 64-tile

  for (int tt = 0; tt < TT128; ++tt) {
    const int cur = tt & 1;
    if (tt + 1 < TT128)
      stage(cur ^ 1, (tt + 1 < TA128) ? tt + 1 : tt + 1 - TA128);
    const bool pA = tt < TA128;
    const int t_in = pA ? tt : tt - TA128;
    const int qt = pA ? qtA : qtB;
    const int kt64 = 2 * t_in + g;  // this group's 64-kv subtile index

    if (kt64 <= qt) {
      const bf16* Kl = g ? &Ko[cur][0] : &Ke[cur][0];
      const bf16* Vl = g ? &Vo[cur][0] : &Ve[cur][0];
      const bf16x8 q0 = pA ? qfA[0] : qfB[0];
      const bf16x8 q1 = pA ? qfA[1] : qfB[1];

      // ---- QK^T swapped (raw): s[j] rows kv = j*16+g4*4+r, cols q = c16
      f32x4 s[4];
      __builtin_amdgcn_s_setprio(1);
#pragma unroll
      for (int j = 0; j < 4; ++j) {
        bf16x8 kf0 = lds_frag(Kl, j * 16 + c16, g4);
        bf16x8 kf1 = lds_frag(Kl, j * 16 + c16, 4 + g4);
        f32x4 c = f32x4{0.f, 0.f, 0.f, 0.f};
        c = __builtin_amdgcn_mfma_f32_16x16x32_bf16(kf0, q0, c, 0, 0, 0);
        c = __builtin_amdgcn_mfma_f32_16x16x32_bf16(kf1, q1, c, 0, 0, 0);
        s[j] = c;
      }
      __builtin_amdgcn_s_setprio(0);
      if (kt64 == qt) {  // diagonal subtile
#pragma unroll
        for (int j = 0; j < 4; ++j)
#pragma unroll
          for (int r = 0; r < 4; ++r)
            if (j * 16 + g4 * 4 + r > ql) s[j][r] = -INFINITY;
      }
      // ---- tile max of the 16 in-lane scores + 2 shfl
      f32x4 t01 = vmax4(s[0], s[1]);
      f32x4 t23 = vmax4(s[2], s[3]);
      f32x4 tv = vmax4(t01, t23);
      float v = fmaxf(fmaxf(tv[0], tv[1]), fmaxf(tv[2], tv[3]));
      v = fmaxf(v, __shfl_xor(v, 16));
      v = fmaxf(v, __shfl_xor(v, 32));
      // ---- defer-max: skip rescale when bounded (p <= 2^8)
      if (!__all(v <= mm + THR)) {
        const float mn = fmaxf(mm, v);
        const float scl = __builtin_amdgcn_exp2f(SC2 * (mm - mn));
        float sc4[4];
#pragma unroll
        for (int r = 0; r < 4; ++r) sc4[r] = __shfl(scl, g4 * 4 + r);
#pragma unroll
        for (int n = 0; n < 4; ++n)
#pragma unroll
          for (int r = 0; r < 4; ++r) acc[n][r] *= sc4[r];
#pragma unroll
        for (int r = 0; r < 4; ++r) lsum4[r] *= sc4[r];
        mm = mn;
      }
      const float nb = SC2 * mm;
      // ---- exp + spill P (b64 per 4 consecutive kv)
      bf16* P = &Pb[w][0];
#pragma unroll
      for (int j = 0; j < 4; ++j) {
        bf16x4 pk;
#pragma unroll
        for (int r = 0; r < 4; ++r)
          pk[r] = (bf16)__builtin_amdgcn_exp2f(fmaf(s[j][r], SC2, -nb));
        const int col = j * 16 + g4 * 4;
        *(bf16x4*)&P[c16 * 64 + (((col >> 3) ^ (c16 & 7)) << 3) + (col & 7)] = pk;
      }
      // ---- PV + row-sum via MFMA
      bf16x8 pa0 = lds_frag(P, c16, g4);
      bf16x8 pa1 = lds_frag(P, c16, 4 + g4);
      __builtin_amdgcn_s_setprio(1);
#pragma unroll
      for (int n = 0; n < 4; ++n) {
        bf16x8 vf0 = lds_frag(Vl, n * 16 + c16, g4);
        bf16x8 vf1 = lds_frag(Vl, n * 16 + c16, 4 + g4);
        acc[n] = __builtin_amdgcn_mfma_f32_16x16x32_bf16(pa0, vf0, acc[n], 0, 0, 0);
        acc[n] = __builtin_amdgcn_mfma_f32_16x16x32_bf16(pa1, vf1, acc[n], 0, 0, 0);
      }
      lsum4 = __builtin_amdgcn_mfma_f32_16x16x32_bf16(pa0, ones, lsum4, 0, 0, 0);
      lsum4 = __builtin_amdgcn_mfma_f32_16x16x32_bf16(pa1, ones, lsum4, 0, 0, 0);
      __builtin_amdgcn_s_setprio(0);
    }

    const bool mergeA = (tt == TA128 - 1);
    const bool mergeB = (tt == TT128 - 1);
    if (mergeA || mergeB) {
      const int qb0 = (mergeA ? qtA : qtB) * 64;
      __syncthreads();  // all compute done; P slots free for merge reuse
      float* ml = (float*)&Pb[wq][0];   // [0..15]=mB per q-row, [16..31]=lB
      bf16* xa = &Pb[4 + wq][0];        // accB bf16 [16 q][64 cols]
      if (g == 1) {
        if (g4 == 0) ml[c16] = mm;
        if (c16 == 0) {
#pragma unroll
          for (int r = 0; r < 4; ++r) ml[16 + g4 * 4 + r] = lsum4[r];
        }
#pragma unroll
        for (int n = 0; n < 4; ++n)
#pragma unroll
          for (int r = 0; r < 4; ++r)
            xa[(g4 * 4 + r) * 64 + n * 16 + c16] = (bf16)acc[n][r];
      }
      __syncthreads();  // B's state visible
      if (g == 0) {
#pragma unroll
        for (int r = 0; r < 4; ++r) {
          const int q = g4 * 4 + r;
          const float mA = __shfl(mm, q);
          const float mB = ml[q];
          const float lB = ml[16 + q];
          const float mt = fmaxf(mA, mB);
          const float fA = __builtin_amdgcn_exp2f(SC2 * (mA - mt));
          const float fB = __builtin_amdgcn_exp2f(SC2 * (mB - mt));
          const float inv = 1.f / (lsum4[r] * fA + lB * fB);
#pragma unroll
          for (int n = 0; n < 4; ++n) {
            const float accB = (float)xa[q * 64 + n * 16 + c16];
            const float o = (acc[n][r] * fA + accB * fB) * inv;
            ob[(size_t)(b * SEQ + qb0 + wq * 16 + q) * DMODEL +
               h * DKH + n * 16 + c16] = (bf16)o;
          }
        }
      }
      // reset both groups for next q-tile
      mm = -INFINITY;
      lsum4 = f32x4{0.f, 0.f, 0.f, 0.f};
#pragma unroll
      for (int n = 0; n < 4; ++n) acc[n] = f32x4{0.f, 0.f, 0.f, 0.f};
    }
    __syncthreads();  // protects P rewrite + dbuf flip (also after merge reads)
  }
}

extern "C" void kernel_launch(void* const* d_in, const int* in_sizes, int n_in,
                              void* d_out, int out_size, void* d_ws, size_t ws_size,
                              hipStream_t stream) {
  const float* x  = (const float*)d_in[0];
  const float* Wq = (const float*)d_in[1];
  const float* Wk = (const float*)d_in[2];
  const float* Wv = (const float*)d_in[3];
  const float* Wo = (const float*)d_in[4];
  float* out = (float*)d_out;
  char* ws = (char*)d_ws;
  const size_t MB = (size_t)1 << 20;

  // wqb/wkb/wvb contiguous -> one [3072][1024] weight matrix for fused QKV
  bf16* xb   = (bf16*)(ws + 0 * MB);   // 8MB
  bf16* wqb  = (bf16*)(ws + 8 * MB);   // 2MB
  bf16* wkb  = (bf16*)(ws + 10 * MB);  // 2MB
  bf16* wvb  = (bf16*)(ws + 12 * MB);  // 2MB
  bf16* wob  = (bf16*)(ws + 14 * MB);  // 2MB
  bf16* qbuf = (bf16*)(ws + 16 * MB);  // 8MB
  bf16* kbuf = (bf16*)(ws + 24 * MB);  // 8MB
  bf16* vTb  = (bf16*)(ws + 32 * MB);  // 8MB, [b][h][dk][s]
  bf16* abuf = (bf16*)(ws + 40 * MB);  // 8MB

  cvt5_kernel<<<8192, 256, 0, stream>>>(x, Wq, Wk, Wv, Wo, xb, wqb, wkb, wvb, wob);

  // fused QKV projection: N = 3072, 768 blocks
  gemm_nt<3><<<dim3(3072 / 128, 4096 / 128), 256, 0, stream>>>(
      xb, wqb, nullptr, qbuf, kbuf, vTb, 4096, 3072, 1024);

  attn_kernel<<<dim3(512), 512, 0, stream>>>(qbuf, kbuf, vTb, abuf);

  gemm_nt<0><<<dim3(1024 / 128, 4096 / 128), 256, 0, stream>>>(
      abuf, wob, out, nullptr, nullptr, nullptr, 4096, 1024, 1024);
}